// Round 13
// baseline (4016.945 us; speedup 1.0000x reference)
//
#include <hip/hip_runtime.h>

// ---------------------------------------------------------------------------
// ViT-S/16 forward, bf16 MFMA everywhere, f32 residual stream.
// Round 13: B-STATIONARY barrier-free GEMM. Six rounds of 2-phase variants
// all pinned at MfmaUtil 13-14% — the per-K-step stage+vmcnt+barrier round
// trip (m233: 72% of time) is structural at K=384 (12 steps). Weights fit in
// LDS: load the 64-col W-stripe once (25-98KB), then a barrier-free main loop
// (A from global/L2, B from swizzled LDS, acc in VGPRs), m-loop amortizes.
// ---------------------------------------------------------------------------

typedef unsigned short u16;
typedef __attribute__((ext_vector_type(8))) short short8;   // 8 bf16 MFMA A/B frag
typedef __attribute__((ext_vector_type(4))) float f32x4;    // MFMA C/D frag
typedef __attribute__((ext_vector_type(4))) unsigned short u16x4;
typedef __attribute__((ext_vector_type(2))) unsigned short u16x2;

#define D_      384
#define NH      6
#define DEPTH_  12
#define NP_     196
#define NT_     197
#define B_      64
#define DFF_    1536
#define M_REAL  (B_*NT_)      // 12608
#define M_PAD   12800         // 50*256
#define M_PATCH (B_*NP_)      // 12544 = 98*128

__device__ __forceinline__ float bf2f(u16 u){
  unsigned int i = ((unsigned int)u) << 16;
  return __builtin_bit_cast(float, i);
}
__device__ __forceinline__ u16 f2bf(float f){
  unsigned int i = __builtin_bit_cast(unsigned int, f);
  i = (i + 0x7FFFu + ((i >> 16) & 1u)) >> 16;   // RNE
  return (u16)i;
}
__device__ __forceinline__ float gelu_f(float x){
  float t = x * (1.595769122f + 0.0713548162726f * x * x);
  return x / (1.f + __expf(-t));
}

#define GLOAD_LDS16(g, l) __builtin_amdgcn_global_load_lds( \
    (const __attribute__((address_space(1))) void*)(g),      \
    (__attribute__((address_space(3))) void*)(l), 16, 0, 0)

#define MFMA_BF16(a, b, c) __builtin_amdgcn_mfma_f32_16x16x32_bf16((a), (b), (c), 0, 0, 0)

// ---------------------------------------------------------------------------
// Merged weight transpose: 7 jobs. src (K,Nsrc) f32 -> (N,K) bf16
// ---------------------------------------------------------------------------
struct TJobs {
  const float* src[7];
  u16*         dst[7];
  int          N[7], K[7], Nsrc[7];
  long long    ss[7], ds[7];
  int          cnt[7];
};

__global__ __launch_bounds__(256) void transpose_all(TJobs J)
{
  __shared__ float tile[32][33];
  int local = blockIdx.x;
  int j = 0;
  while (local >= J.cnt[j]) { local -= J.cnt[j]; ++j; }
  int nbx = J.N[j] >> 5, nby = J.K[j] >> 5;
  int z   = local / (nbx * nby);
  int rem = local - z * nbx * nby;
  int by = rem / nbx, bx = rem - by * nbx;
  const float* src = J.src[j] + (long long)z * J.ss[j];
  u16* dst = J.dst[j] + (long long)z * J.ds[j];
  int K = J.K[j], Nsrc = J.Nsrc[j];
  int tx = threadIdx.x, ty = threadIdx.y;
  int n0 = bx * 32, k0 = by * 32;
#pragma unroll
  for (int i = 0; i < 4; ++i){
    float v = 0.f;
    if (n0 + tx < Nsrc) v = src[(size_t)(k0 + ty + i*8) * Nsrc + n0 + tx];
    tile[ty + i*8][tx] = v;
  }
  __syncthreads();
#pragma unroll
  for (int i = 0; i < 4; ++i)
    dst[(size_t)(n0 + ty + i*8) * K + k0 + tx] = f2bf(tile[tx][ty + i*8]);
}

// ---------------------------------------------------------------------------
// Patch extraction: x (B,3,224,224) f32 -> patches (B*196, 768) bf16
// ---------------------------------------------------------------------------
__global__ __launch_bounds__(256) void patch_extract(const float* __restrict__ x,
                                                     u16* __restrict__ patches)
{
  int r = blockIdx.x;
  int b = r / NP_, p = r % NP_;
  int gy = p / 14, gx = p % 14;
  int t = threadIdx.x;
  int py = t >> 4, px = t & 15;
#pragma unroll
  for (int c = 0; c < 3; ++c){
    float v = x[(((size_t)b*3 + c)*224 + gy*16 + py)*224 + gx*16 + px];
    patches[(size_t)r*768 + c*256 + t] = f2bf(v);
  }
}

// ---------------------------------------------------------------------------
// B-STATIONARY GEMM: C(M,N) = A(M,K)bf16 * Bt(N,K)bf16 (+bias)
// Block owns a BN=64 N-stripe of B in LDS (loaded ONCE, XOR-8 chunk swizzle),
// then loops over mpg M-tiles of BM=256 with a BARRIER-FREE K-loop:
// A frags from global (L2-resident; 16 rows x 64B full lines per instr),
// B frags via conflict-free ds_read_b128, acc in VGPRs.
// 8 waves = 4M x 2N (wave 64x32, MI=4, NJ=2). KL = K/KS (u16), mult of 32,
// NK=KL/32 fully unrolled. grid.x = nstripes*G (XCD-swizzled), grid.y = KS.
// MODE 0: bf16=acc+bias ; 2: gelu bf16 ; 4: bf16 slice at kz*sstride.
// ---------------------------------------------------------------------------
template<int MODE, int KL, int KS>
__global__ __launch_bounds__(512, 4) void gemm_bs(const u16* __restrict__ A,
                                                  const u16* __restrict__ Bt,
                                                  const float* __restrict__ bias,
                                                  u16* __restrict__ outb,
                                                  int N, int K, int nstripes,
                                                  int Mtiles, int mpg, size_t sstride)
{
  constexpr int BN  = 64;
  constexpr int MI  = 4;            // wave 64x32
  constexpr int NJ  = 2;
  constexpr int NCH = KL / 8;       // 16B chunks per B row
  constexpr int NK  = KL / 32;
  constexpr int PITCH = 40;         // epilogue Cs row pitch (u16)
  __shared__ u16 Bs[BN * KL];
  __shared__ u16 Cs[8 * 16 * PITCH];

  int tid = threadIdx.x, w = tid >> 6, lane = tid & 63;

  // bijective XCD-chunked swizzle (m204); stripe-fastest so one m-group's
  // blocks colocate on an XCD (A-panel L2 sharing)
  int nwg = gridDim.x;
  int q = nwg >> 3, r = nwg & 7;
  int xcd = blockIdx.x & 7, slot = blockIdx.x >> 3;
  int wgid = (xcd < r ? xcd*(q+1) : r*(q+1) + (xcd - r)*q) + slot;
  int g  = wgid / nstripes;
  int ns = wgid - g * nstripes;
  int n0 = ns * BN;
  int kz = (KS > 1) ? blockIdx.y : 0;
  int koff = kz * KL;

  int wr = w >> 1, wc = w & 1;
  int fr = lane & 15, fk = lane >> 4;
  int frs = fr & 7;

  // ---- stage B stripe once (linear LDS dest, pre-swizzled global source) ----
  constexpr int ROUNDS = (BN * NCH) / 512;
#pragma unroll
  for (int rd = 0; rd < ROUNDS; ++rd){
    int idx = rd*512 + tid;
    int row = idx / NCH;
    int pos = idx - row * NCH;
    int sc  = (pos & ~7) | ((pos & 7) ^ (row & 7));
    GLOAD_LDS16(Bt + (size_t)(n0 + row) * K + koff + sc*8, Bs + (size_t)idx * 8);
  }
  __syncthreads();   // drains vmcnt; ONLY barrier in the kernel

  int rb0 = wc*32 + fr;             // B row for j=0 (j adds 16; &7 unchanged)
  u16* Cw = Cs + w * (16 * PITCH);
  u16* outp = (MODE == 4) ? outb + (size_t)kz * sstride : outb;
  int cr = (lane >> 4) << 2;
  int cc = lane & 15;
  int lr = lane >> 2, lc = lane & 3;

  for (int mt = 0; mt < mpg; ++mt){
    int m_tile = g * mpg + mt;
    if (m_tile >= Mtiles) break;
    int m0 = m_tile * 256;

    f32x4 acc[MI][NJ];
#pragma unroll
    for (int i = 0; i < MI; ++i)
#pragma unroll
      for (int j = 0; j < NJ; ++j) acc[i][j] = (f32x4){0.f,0.f,0.f,0.f};

    const u16* Ab = A + (size_t)(m0 + wr*64 + fr) * K + koff + fk*8;

#pragma unroll
    for (int t = 0; t < NK; ++t){
      short8 av[MI];
#pragma unroll
      for (int i = 0; i < MI; ++i)
        av[i] = *(const short8*)(Ab + (size_t)(i*16) * K + t*32);
      short8 bv[NJ];
      int c  = t*4 + fk;
      int p  = (c & ~7) | ((c & 7) ^ frs);
#pragma unroll
      for (int j = 0; j < NJ; ++j)
        bv[j] = *(const short8*)&Bs[(rb0 + j*16) * KL + p*8];
#pragma unroll
      for (int i = 0; i < MI; ++i)
#pragma unroll
        for (int j = 0; j < NJ; ++j)
          acc[i][j] = MFMA_BF16(av[i], bv[j], acc[i][j]);
    }

    // epilogue: per 16-row pass, LDS-stage then 64B-line stores (wave-local)
#pragma unroll
    for (int i = 0; i < MI; ++i){
#pragma unroll
      for (int j = 0; j < NJ; ++j){
        int ccol = n0 + wc*32 + j*16 + cc;
        float bv_ = (bias && kz == 0) ? bias[ccol] : 0.f;
#pragma unroll
        for (int e = 0; e < 4; ++e){
          float v = acc[i][j][e] + bv_;
          if (MODE == 2) v = gelu_f(v);
          Cw[(cr + e) * PITCH + j*16 + cc] = f2bf(v);
        }
      }
      short8 val = *(const short8*)&Cw[lr * PITCH + lc*8];
      size_t gm = (size_t)(m0 + wr*64 + i*16 + lr);
      *(short8*)&outp[gm * N + n0 + wc*32 + lc*8] = val;
    }
  }
}

// ---------------------------------------------------------------------------
// 2-phase GEMM (r12-proven) for patch-embed and head.
// ---------------------------------------------------------------------------
template<int MODE, int BM, int BN, int KS, int NW>
__global__ __launch_bounds__(NW*64) void gemm_k(const u16* __restrict__ A,
                                                const u16* __restrict__ Bt,
                                                const float* __restrict__ bias,
                                                u16* __restrict__ outb,
                                                float* __restrict__ outf,
                                                int N, int K, int nbx, size_t sstride)
{
  constexpr int WAVES_M = (NW == 8) ? 4 : 2;
  constexpr int WM = BM / WAVES_M;
  constexpr int WN = BN / 2;
  constexpr int MI = WM / 16;
  constexpr int NJ = WN / 16;
  constexpr int CA = BM / (16 * NW);
  constexpr int CB = BN / (16 * NW);
  constexpr int L  = CA + CB;
  __shared__ u16 lds[2*(BM+BN)*32];
  u16* As = lds;
  u16* Bs = lds + 2*BM*32;
  int tid = threadIdx.x;
  int w = tid >> 6, lane = tid & 63;

  int nwg = gridDim.x;
  int q = nwg >> 3, r = nwg & 7;
  int xcd = blockIdx.x & 7, slot = blockIdx.x >> 3;
  int wgid = (xcd < r ? xcd*(q+1) : r*(q+1) + (xcd - r)*q) + slot;
  int m0 = (wgid / nbx) * BM;
  int n0 = (wgid % nbx) * BN;
  int kz = (KS > 1) ? blockIdx.y : 0;
  int Kl = K / KS;
  int koff = kz * Kl;
  int wr = w >> 1, wc = w & 1;

  f32x4 acc[MI][NJ];
#pragma unroll
  for (int i = 0; i < MI; ++i)
#pragma unroll
    for (int j = 0; j < NJ; ++j) acc[i][j] = (f32x4){0.f,0.f,0.f,0.f};

  int srow = lane >> 2;
  int skc  = ((lane & 3) ^ ((lane >> 3) & 3)) * 8;
  const u16* Ag = A  + (size_t)(m0 + w*16 + srow) * K + koff + skc;
  const u16* Bg = Bt + (size_t)(n0 + w*16 + srow) * K + koff + skc;

  int fr  = lane & 15;
  int fsw = ((lane >> 4) ^ ((lane >> 1) & 3)) << 3;

  auto stage = [&](int bi, int kt){
    u16* Ad = As + bi*(BM*32) + (w*16)*32;
    u16* Bd = Bs + bi*(BN*32) + (w*16)*32;
#pragma unroll
    for (int c = 0; c < CA; ++c)
      GLOAD_LDS16(Ag + (size_t)(c*16*NW)*K + kt, Ad + c*16*NW*32);
#pragma unroll
    for (int c = 0; c < CB; ++c)
      GLOAD_LDS16(Bg + (size_t)(c*16*NW)*K + kt, Bd + c*16*NW*32);
  };
  auto compute = [&](int bi){
    const u16* Ab = As + bi*(BM*32);
    const u16* Bb = Bs + bi*(BN*32);
    short8 af[MI], bfr[NJ];
#pragma unroll
    for (int i = 0; i < MI; ++i)
      af[i]  = *(const short8*)&Ab[(wr*WM + i*16 + fr)*32 + fsw];
#pragma unroll
    for (int j = 0; j < NJ; ++j)
      bfr[j] = *(const short8*)&Bb[(wc*WN + j*16 + fr)*32 + fsw];
#pragma unroll
    for (int i = 0; i < MI; ++i)
#pragma unroll
      for (int j = 0; j < NJ; ++j)
        acc[i][j] = MFMA_BF16(af[i], bfr[j], acc[i][j]);
  };

#define WAIT_L()  do { \
    if constexpr (L == 2)      asm volatile("s_waitcnt vmcnt(2)" ::: "memory"); \
    else if constexpr (L == 3) asm volatile("s_waitcnt vmcnt(3)" ::: "memory"); \
    else                       asm volatile("s_waitcnt vmcnt(4)" ::: "memory"); \
  } while (0)

  int nk = Kl >> 5;
  stage(0, 0);
  for (int t = 0; t < nk; t += 2){
    stage(1, (t + 1) * 32);
    __builtin_amdgcn_sched_barrier(0);
    WAIT_L();
    __builtin_amdgcn_s_barrier();
    asm volatile("" ::: "memory");
    compute(0);
    __builtin_amdgcn_sched_barrier(0);
    __builtin_amdgcn_s_barrier();
    if (t + 2 < nk){
      stage(0, (t + 2) * 32);
      __builtin_amdgcn_sched_barrier(0);
      WAIT_L();
    } else {
      __builtin_amdgcn_sched_barrier(0);
      asm volatile("s_waitcnt vmcnt(0)" ::: "memory");
    }
    __builtin_amdgcn_s_barrier();
    asm volatile("" ::: "memory");
    compute(1);
    __builtin_amdgcn_sched_barrier(0);
    __builtin_amdgcn_s_barrier();
  }
#undef WAIT_L

  int cr = (lane >> 4) << 2;
  int cc = lane & 15;

  if constexpr (MODE == 3){
#pragma unroll
    for (int j = 0; j < NJ; ++j){
      int c = n0 + wc*WN + j*16 + cc;
      float bv = bias ? bias[c] : 0.f;
#pragma unroll
      for (int i = 0; i < MI; ++i){
        int rbase = m0 + wr*WM + i*16 + cr;
#pragma unroll
        for (int e = 0; e < 4; ++e){
          float v = acc[i][j][e] + bv;
          if (c < N) outf[(size_t)(rbase + e) * N + c] = v;
        }
      }
    }
  } else {
    constexpr int PITCH = WN + 8;
    u16* Cs = lds + w * (16 * PITCH);
    u16* outp = outb;
    int lr0 = lane >> 3;
    int lc  = lane & 7;
#pragma unroll
    for (int i = 0; i < MI; ++i){
#pragma unroll
      for (int j = 0; j < NJ; ++j){
        int c = n0 + wc*WN + j*16 + cc;
        float bv = (bias && kz == 0) ? bias[c] : 0.f;
#pragma unroll
        for (int e = 0; e < 4; ++e){
          float v = acc[i][j][e] + bv;
          if (MODE == 2) v = gelu_f(v);
          Cs[(cr + e) * PITCH + j*16 + cc] = f2bf(v);
        }
      }
#pragma unroll
      for (int p = 0; p < 2; ++p){
        int lrr = p*8 + lr0;
        short8 val = *(const short8*)&Cs[lrr * PITCH + lc*8];
        size_t gm = (size_t)(m0 + wr*WM + i*16 + lrr);
        *(short8*)&outp[gm * N + n0 + wc*WN + lc*8] = val;
      }
    }
  }
}

// ---------------------------------------------------------------------------
// LayerNorm rows (plain): in f32 (rows,384) stride rstride -> out bf16
// ---------------------------------------------------------------------------
__global__ __launch_bounds__(256) void ln_rows(const float* __restrict__ in,
                                               const float* __restrict__ gw,
                                               const float* __restrict__ gb,
                                               u16* __restrict__ out, int rows,
                                               size_t rstride)
{
  int m = blockIdx.x * 4 + (threadIdx.x >> 6);
  int lane = threadIdx.x & 63;
  if (m >= rows) return;
  const float* r = in + (size_t)m * rstride;
  float4 v0 = *(const float4*)(r + lane*4);
  float2 v1 = *(const float2*)(r + 256 + lane*2);
  float sum = v0.x+v0.y+v0.z+v0.w+v1.x+v1.y;
  float sq  = v0.x*v0.x+v0.y*v0.y+v0.z*v0.z+v0.w*v0.w+v1.x*v1.x+v1.y*v1.y;
#pragma unroll
  for (int d = 1; d < 64; d <<= 1){ sum += __shfl_xor(sum, d); sq += __shfl_xor(sq, d); }
  float mean = sum * (1.f/D_);
  float rs = rsqrtf(sq*(1.f/D_) - mean*mean + 1e-5f);
  float4 w0 = *(const float4*)(gw + lane*4);
  float2 w1 = *(const float2*)(gw + 256 + lane*2);
  float4 b0 = *(const float4*)(gb + lane*4);
  float2 b1v= *(const float2*)(gb + 256 + lane*2);
  u16x4 o4 = { f2bf((v0.x-mean)*rs*w0.x + b0.x), f2bf((v0.y-mean)*rs*w0.y + b0.y),
               f2bf((v0.z-mean)*rs*w0.z + b0.z), f2bf((v0.w-mean)*rs*w0.w + b0.w) };
  u16x2 o2 = { f2bf((v1.x-mean)*rs*w1.x + b1v.x), f2bf((v1.y-mean)*rs*w1.y + b1v.y) };
  *(u16x4*)(out + (size_t)m*D_ + lane*4) = o4;
  *(u16x2*)(out + (size_t)m*D_ + 256 + lane*2) = o2;
}

// ---------------------------------------------------------------------------
// LayerNorm + slice-reduce: h' = in + s0 + s1 (bf16 slices); out = LN(h');
// ---------------------------------------------------------------------------
__global__ __launch_bounds__(256) void ln_rows_add(const float* __restrict__ in,
                                                   const u16* __restrict__ s0,
                                                   const u16* __restrict__ s1,
                                                   const float* __restrict__ gw,
                                                   const float* __restrict__ gb,
                                                   u16* __restrict__ out,
                                                   float* __restrict__ hout,
                                                   int rows, size_t rstride)
{
  int m = blockIdx.x * 4 + (threadIdx.x >> 6);
  int lane = threadIdx.x & 63;
  if (m >= rows) return;
  const float* r = in + (size_t)m * rstride;
  const u16* p0 = s0 + (size_t)m * rstride;
  const u16* p1 = s1 + (size_t)m * rstride;
  float4 v0 = *(const float4*)(r + lane*4);
  float2 v1 = *(const float2*)(r + 256 + lane*2);
  u16x4 a0 = *(const u16x4*)(p0 + lane*4);
  u16x2 a1 = *(const u16x2*)(p0 + 256 + lane*2);
  u16x4 c0 = *(const u16x4*)(p1 + lane*4);
  u16x2 c1 = *(const u16x2*)(p1 + 256 + lane*2);
  float x0 = v0.x + bf2f(a0.x) + bf2f(c0.x);
  float x1 = v0.y + bf2f(a0.y) + bf2f(c0.y);
  float x2 = v0.z + bf2f(a0.z) + bf2f(c0.z);
  float x3 = v0.w + bf2f(a0.w) + bf2f(c0.w);
  float x4 = v1.x + bf2f(a1.x) + bf2f(c1.x);
  float x5 = v1.y + bf2f(a1.y) + bf2f(c1.y);
  float sum = x0+x1+x2+x3+x4+x5;
  float sq  = x0*x0+x1*x1+x2*x2+x3*x3+x4*x4+x5*x5;
#pragma unroll
  for (int d = 1; d < 64; d <<= 1){ sum += __shfl_xor(sum, d); sq += __shfl_xor(sq, d); }
  float mean = sum * (1.f/D_);
  float rs = rsqrtf(sq*(1.f/D_) - mean*mean + 1e-5f);
  float4 w0 = *(const float4*)(gw + lane*4);
  float2 w1 = *(const float2*)(gw + 256 + lane*2);
  float4 b0 = *(const float4*)(gb + lane*4);
  float2 b1v= *(const float2*)(gb + 256 + lane*2);
  u16x4 o4 = { f2bf((x0-mean)*rs*w0.x + b0.x), f2bf((x1-mean)*rs*w0.y + b0.y),
               f2bf((x2-mean)*rs*w0.z + b0.z), f2bf((x3-mean)*rs*w0.w + b0.w) };
  u16x2 o2 = { f2bf((x4-mean)*rs*w1.x + b1v.x), f2bf((x5-mean)*rs*w1.y + b1v.y) };
  *(u16x4*)(out + (size_t)m*D_ + lane*4) = o4;
  *(u16x2*)(out + (size_t)m*D_ + 256 + lane*2) = o2;
  if (hout){
    float* ho = hout + (size_t)m * rstride;
    float4 h0 = {x0,x1,x2,x3};
    float2 h1 = {x4,x5};
    *(float4*)(ho + lane*4) = h0;
    *(float2*)(ho + 256 + lane*2) = h1;
  }
}

// ---------------------------------------------------------------------------
// Assemble h (M_PAD,384) f32
// ---------------------------------------------------------------------------
__global__ __launch_bounds__(256) void assemble_h(const u16* __restrict__ pe,
                                                  const float* __restrict__ gw,
                                                  const float* __restrict__ gb,
                                                  const float* __restrict__ pos,
                                                  const float* __restrict__ cls,
                                                  float* __restrict__ h)
{
  int m = blockIdx.x * 4 + (threadIdx.x >> 6);
  int lane = threadIdx.x & 63;
  if (m >= M_PAD) return;
  float* ho = h + (size_t)m * D_;
  if (m >= M_REAL){
    float4 z = {0.f,0.f,0.f,0.f};
    *(float4*)(ho + lane*4) = z;
    float2 z2 = {0.f,0.f};
    *(float2*)(ho + 256 + lane*2) = z2;
    return;
  }
  int b = m / NT_, t = m % NT_;
  const float* pr = pos + (size_t)t * D_;
  float4 p0 = *(const float4*)(pr + lane*4);
  float2 p1 = *(const float2*)(pr + 256 + lane*2);
  if (t == 0){
    float4 c0 = *(const float4*)(cls + lane*4);
    float2 c1 = *(const float2*)(cls + 256 + lane*2);
    float4 r0 = {c0.x+p0.x, c0.y+p0.y, c0.z+p0.z, c0.w+p0.w};
    float2 r1 = {c1.x+p1.x, c1.y+p1.y};
    *(float4*)(ho + lane*4) = r0;
    *(float2*)(ho + 256 + lane*2) = r1;
  } else {
    const u16* per = pe + (size_t)(b*NP_ + (t-1)) * D_;
    u16x4 a0 = *(const u16x4*)(per + lane*4);
    u16x2 a1 = *(const u16x2*)(per + 256 + lane*2);
    float x0=bf2f(a0.x), x1=bf2f(a0.y), x2=bf2f(a0.z), x3=bf2f(a0.w), x4=bf2f(a1.x), x5=bf2f(a1.y);
    float sum = x0+x1+x2+x3+x4+x5;
    float sq  = x0*x0+x1*x1+x2*x2+x3*x3+x4*x4+x5*x5;
#pragma unroll
    for (int d = 1; d < 64; d <<= 1){ sum += __shfl_xor(sum, d); sq += __shfl_xor(sq, d); }
    float mean = sum * (1.f/D_);
    float rs = rsqrtf(sq*(1.f/D_) - mean*mean + 1e-5f);
    float4 w0 = *(const float4*)(gw + lane*4);
    float2 w1 = *(const float2*)(gw + 256 + lane*2);
    float4 b0 = *(const float4*)(gb + lane*4);
    float2 b1v= *(const float2*)(gb + 256 + lane*2);
    float4 r0 = { (x0-mean)*rs*w0.x + b0.x + p0.x, (x1-mean)*rs*w0.y + b0.y + p0.y,
                  (x2-mean)*rs*w0.z + b0.z + p0.z, (x3-mean)*rs*w0.w + b0.w + p0.w };
    float2 r1 = { (x4-mean)*rs*w1.x + b1v.x + p1.x, (x5-mean)*rs*w1.y + b1v.y + p1.y };
    *(float4*)(ho + lane*4) = r0;
    *(float2*)(ho + 256 + lane*2) = r1;
  }
}

// ---------------------------------------------------------------------------
// Fused attention over packed qkv (M,1152): [q(384) | k(384) | v(384)]
// ---------------------------------------------------------------------------
__global__ __launch_bounds__(256) void attn_k(const u16* __restrict__ qkv,
                                              u16* __restrict__ o)
{
  __shared__ u16 Ks[208*72];
  __shared__ u16 Vt[64*232];
  __shared__ u16 Ps[4][16*40];
  int bh = blockIdx.x;
  int b = bh / NH, hh = bh % NH;
  int tid = threadIdx.x, w = tid >> 6, lane = tid & 63;
  const u16* kbase = qkv + (size_t)b*NT_*1152 + 384 + hh*64;
  const u16* vbase = kbase + 384;

  int jr = tid >> 3, col = (tid & 7) * 8;
#pragma unroll
  for (int it = 0; it < 7; ++it){
    int j = it*32 + jr;
    if (j < 208){
      uint4 val = {0u,0u,0u,0u};
      if (j < 197) val = *(const uint4*)(kbase + (size_t)j*1152 + col);
      *(uint4*)&Ks[j*72 + col] = val;
    }
  }
#pragma unroll
  for (int it = 0; it < 7; ++it){
    int j = it*32 + jr;
    union { uint4 v; u16 s[8]; } u;
    u.v.x = 0u; u.v.y = 0u; u.v.z = 0u; u.v.w = 0u;
    if (j < 197) u.v = *(const uint4*)(vbase + (size_t)j*1152 + col);
#pragma unroll
    for (int e = 0; e < 8; ++e) Vt[(size_t)(col+e)*232 + j] = u.s[e];
  }
  __syncthreads();

  u16* myP = Ps[w];
  int fr = lane & 15, fk = lane >> 4;

  for (int qt = w; qt < 13; qt += 4){
    const u16* qrow = qkv + (size_t)(b*NT_ + qt*16 + fr)*1152 + hh*64 + fk*8;
    short8 aq0 = *(const short8*)qrow;
    short8 aq1 = *(const short8*)(qrow + 32);

    f32x4 s[13];
#pragma unroll
    for (int jt = 0; jt < 13; ++jt){
      const u16* kr = &Ks[(jt*16 + fr)*72 + fk*8];
      short8 bk0 = *(const short8*)kr;
      short8 bk1 = *(const short8*)(kr + 32);
      f32x4 z = {0.f,0.f,0.f,0.f};
      z = MFMA_BF16(aq0, bk0, z);
      z = MFMA_BF16(aq1, bk1, z);
      s[jt] = z;
    }

#pragma unroll
    for (int e = 0; e < 4; ++e){
      float mx = -1e30f;
#pragma unroll
      for (int jt = 0; jt < 13; ++jt){
        int cj = jt*16 + fr;
        float v = (cj < NT_) ? s[jt][e]*0.125f : -1e30f;
        s[jt][e] = v;
        mx = fmaxf(mx, v);
      }
#pragma unroll
      for (int d = 1; d < 16; d <<= 1) mx = fmaxf(mx, __shfl_xor(mx, d));
      float su = 0.f;
#pragma unroll
      for (int jt = 0; jt < 13; ++jt){
        float p = __expf(s[jt][e] - mx);
        s[jt][e] = p; su += p;
      }
#pragma unroll
      for (int d = 1; d < 16; d <<= 1) su += __shfl_xor(su, d);
      float ri = 1.f / su;
#pragma unroll
      for (int jt = 0; jt < 13; ++jt) s[jt][e] *= ri;
    }

    f32x4 oacc[4];
#pragma unroll
    for (int dt = 0; dt < 4; ++dt) oacc[dt] = (f32x4){0.f,0.f,0.f,0.f};
#pragma unroll
    for (int jc = 0; jc < 7; ++jc){
#pragma unroll
      for (int jtl = 0; jtl < 2; ++jtl){
        int jt = jc*2 + jtl;
#pragma unroll
        for (int e = 0; e < 4; ++e){
          u16 pv = 0;
          if (jt < 13) pv = f2bf(s[jt][e]);
          myP[(fk*4 + e)*40 + jtl*16 + fr] = pv;
        }
      }
      asm volatile("s_waitcnt lgkmcnt(0)" ::: "memory");
      short8 pa = *(const short8*)&myP[fr*40 + fk*8];
#pragma unroll
      for (int dt = 0; dt < 4; ++dt){
        short8 bv = *(const short8*)&Vt[(size_t)(dt*16 + fr)*232 + jc*32 + fk*8];
        oacc[dt] = MFMA_BF16(pa, bv, oacc[dt]);
      }
    }

#pragma unroll
    for (int dt = 0; dt < 4; ++dt)
#pragma unroll
      for (int e = 0; e < 4; ++e){
        int t = qt*16 + fk*4 + e;
        if (t < NT_)
          o[(size_t)(b*NT_ + t)*384 + hh*64 + dt*16 + fr] = f2bf(oacc[dt][e]);
      }
  }
}

// ---------------------------------------------------------------------------
extern "C" void kernel_launch(void* const* d_in, const int* in_sizes, int n_in,
                              void* d_out, int out_size, void* d_ws, size_t ws_size,
                              hipStream_t stream)
{
  (void)in_sizes; (void)n_in; (void)out_size; (void)ws_size;
  const float* x_in    = (const float*)d_in[0];
  const float* W_patch = (const float*)d_in[1];
  const float* b_patch = (const float*)d_in[2];
  const float* ln0_w   = (const float*)d_in[3];
  const float* ln0_b   = (const float*)d_in[4];
  const float* pos_emb = (const float*)d_in[5];
  const float* cls_tok = (const float*)d_in[6];
  const float* ln1_w   = (const float*)d_in[7];
  const float* ln1_b   = (const float*)d_in[8];
  const float* Wq      = (const float*)d_in[9];
  const float* Wkv     = (const float*)d_in[10];
  const float* Wo      = (const float*)d_in[11];
  const float* bo      = (const float*)d_in[12];
  const float* ln2_w   = (const float*)d_in[13];
  const float* ln2_b   = (const float*)d_in[14];
  const float* W1      = (const float*)d_in[15];
  const float* b1      = (const float*)d_in[16];
  const float* W2      = (const float*)d_in[17];
  const float* b2      = (const float*)d_in[18];
  const float* lnf_w   = (const float*)d_in[19];
  const float* lnf_b   = (const float*)d_in[20];
  const float* Whead   = (const float*)d_in[21];
  const float* bhead   = (const float*)d_in[22];

  char* ws = (char*)d_ws;
  size_t off = 0;
  auto nxt = [&](size_t bytes)->char* {
    char* p = ws + off;
    off += (bytes + 255) & ~(size_t)255;
    return p;
  };
  u16*   g_buf   = (u16*)  nxt((size_t)M_PAD * DFF_ * 2);   // also: patches
  float* hbuf    = (float*)nxt((size_t)M_PAD * D_ * 4);
  u16*   abuf    = (u16*)  nxt((size_t)M_PAD * D_ * 2);     // also: patch-embed out
  u16*   qkvbuf  = (u16*)  nxt((size_t)M_PAD * 1152 * 2);
  u16*   obuf    = (u16*)  nxt((size_t)M_PAD * D_ * 2);
  u16*   sbuf    = (u16*)  nxt((size_t)2 * M_PAD * D_ * 2); // split-K slices
  u16*   lncls   = (u16*)  nxt((size_t)B_ * D_ * 2);
  u16*   whT     = (u16*)  nxt((size_t)1024 * D_ * 2);
  u16*   wT      = (u16*)  nxt((size_t)21528576 * 2);

  const size_t SS = (size_t)M_PAD * D_;
  u16* patches = g_buf;
  u16* pebuf   = abuf;
  u16* wpT   = wT;
  u16* wqkvT = wpT   + 294912;
  u16* woT   = wqkvT + 12*442368;
  u16* w1T   = woT   + 12*147456;
  u16* w2T   = w1T   + 12*589824;

  TJobs J;
  auto setj = [&](int i, const float* s, u16* d, int N, int K, int Nsrc,
                  long long ss, long long ds, int nz){
    J.src[i]=s; J.dst[i]=d; J.N[i]=N; J.K[i]=K; J.Nsrc[i]=Nsrc;
    J.ss[i]=ss; J.ds[i]=ds; J.cnt[i]=(N/32)*(K/32)*nz;
  };
  setj(0, W_patch, wpT,             384,  768,  384, 0, 0, 1);
  setj(1, Wq,      wqkvT,           384,  384,  384, 384LL*384,  1152LL*384, 12);
  setj(2, Wkv,     wqkvT + 384*384, 768,  384,  768, 384LL*768,  1152LL*384, 12);
  setj(3, Wo,      woT,             384,  384,  384, 384LL*384,  384LL*384,  12);
  setj(4, W1,      w1T,             1536, 384, 1536, 384LL*1536, 384LL*1536, 12);
  setj(5, W2,      w2T,             384, 1536,  384, 1536LL*384, 1536LL*384, 12);
  setj(6, Whead,   whT,             1024, 384, 1000, 0, 0, 1);
  int tblocks = 0;
  for (int i = 0; i < 7; ++i) tblocks += J.cnt[i];
  transpose_all<<<tblocks, dim3(32,8), 0, stream>>>(J);

  patch_extract<<<M_PATCH, 256, 0, stream>>>(x_in, patches);
  gemm_k<0,128,128,1,8><<<3*(M_PATCH/128), 512, 0, stream>>>(patches, wpT, b_patch, pebuf, nullptr, 384, 768, 3, 0);
  assemble_h<<<M_PAD/4, 256, 0, stream>>>(pebuf, ln0_w, ln0_b, pos_emb, cls_tok, hbuf);

  const int MT = M_PAD / 256;   // 50 m-tiles
  for (int d = 0; d < DEPTH_; ++d){
    if (d == 0)
      ln_rows<<<M_PAD/4, 256, 0, stream>>>(hbuf, ln1_w, ln1_b, abuf, M_PAD, D_);
    else
      ln_rows_add<<<M_PAD/4, 256, 0, stream>>>(hbuf, sbuf, sbuf + SS,
                                               ln1_w + d*384, ln1_b + d*384,
                                               abuf, hbuf, M_PAD, D_);
    // qkv: N=1152, 18 stripes, mpg=3 -> G=17
    gemm_bs<0,384,1><<<dim3(18*17,1), 512, 0, stream>>>(abuf, wqkvT + (size_t)d*442368, nullptr, qkvbuf, 1152, 384, 18, MT, 3, 0);
    attn_k<<<B_*NH, 256, 0, stream>>>(qkvbuf, obuf);
    // wo: N=384, KS=2 (Kl=192), 6 stripes, mpg=2 -> G=25
    gemm_bs<4,192,2><<<dim3(6*25,2), 512, 0, stream>>>(obuf, woT + (size_t)d*147456, bo + d*384, sbuf, 384, 384, 6, MT, 2, SS);
    ln_rows_add<<<M_PAD/4, 256, 0, stream>>>(hbuf, sbuf, sbuf + SS,
                                             ln2_w + d*384, ln2_b + d*384,
                                             abuf, hbuf, M_PAD, D_);
    // ffn1: N=1536, 24 stripes, mpg=3 -> G=17
    gemm_bs<2,384,1><<<dim3(24*17,1), 512, 0, stream>>>(abuf, w1T + (size_t)d*589824, b1 + d*1536, g_buf, 1536, 384, 24, MT, 3, 0);
    // ffn2: N=384, KS=2 (Kl=768), 6 stripes, mpg=2 -> G=25
    gemm_bs<4,768,2><<<dim3(6*25,2), 512, 0, stream>>>(g_buf, w2T + (size_t)d*589824, b2 + d*384, sbuf, 384, 1536, 6, MT, 2, SS);
  }

  ln_rows_add<<<B_/4, 256, 0, stream>>>(hbuf, sbuf, sbuf + SS,
                                        lnf_w, lnf_b, lncls, nullptr,
                                        B_, (size_t)NT_*D_);
  gemm_k<3,64,64,1,4><<<16, 256, 0, stream>>>(lncls, whT, bhead, nullptr, (float*)d_out, 1000, 384, 16, 0);
}

// Round 14
// 1749.105 us; speedup vs baseline: 2.2966x; 2.2966x over previous
//
#include <hip/hip_runtime.h>

// ---------------------------------------------------------------------------
// ViT-S/16 forward, bf16 MFMA everywhere, f32 residual stream.
// Round 14: consolidation. r13's B-stationary failed (1 block/CU, no TLP for
// L2-latency A-loads). Revert to r9's proven 128x128 2-phase GEMM config
// (1804us) + r12's corrected LDS swizzle; attention upgraded to 8 waves.
// ---------------------------------------------------------------------------

typedef unsigned short u16;
typedef __attribute__((ext_vector_type(8))) short short8;   // 8 bf16 MFMA A/B frag
typedef __attribute__((ext_vector_type(4))) float f32x4;    // MFMA C/D frag
typedef __attribute__((ext_vector_type(4))) unsigned short u16x4;
typedef __attribute__((ext_vector_type(2))) unsigned short u16x2;

#define D_      384
#define NH      6
#define DEPTH_  12
#define NP_     196
#define NT_     197
#define B_      64
#define DFF_    1536
#define M_REAL  (B_*NT_)      // 12608
#define M_PAD   12672         // 99*128
#define M_PATCH (B_*NP_)      // 12544 = 98*128

__device__ __forceinline__ float bf2f(u16 u){
  unsigned int i = ((unsigned int)u) << 16;
  return __builtin_bit_cast(float, i);
}
__device__ __forceinline__ u16 f2bf(float f){
  unsigned int i = __builtin_bit_cast(unsigned int, f);
  i = (i + 0x7FFFu + ((i >> 16) & 1u)) >> 16;   // RNE
  return (u16)i;
}
__device__ __forceinline__ float gelu_f(float x){
  float t = x * (1.595769122f + 0.0713548162726f * x * x);
  return x / (1.f + __expf(-t));
}

#define GLOAD_LDS16(g, l) __builtin_amdgcn_global_load_lds( \
    (const __attribute__((address_space(1))) void*)(g),      \
    (__attribute__((address_space(3))) void*)(l), 16, 0, 0)

#define MFMA_BF16(a, b, c) __builtin_amdgcn_mfma_f32_16x16x32_bf16((a), (b), (c), 0, 0, 0)

// ---------------------------------------------------------------------------
// Merged weight transpose: 7 jobs. src (K,Nsrc) f32 -> (N,K) bf16
// ---------------------------------------------------------------------------
struct TJobs {
  const float* src[7];
  u16*         dst[7];
  int          N[7], K[7], Nsrc[7];
  long long    ss[7], ds[7];
  int          cnt[7];
};

__global__ __launch_bounds__(256) void transpose_all(TJobs J)
{
  __shared__ float tile[32][33];
  int local = blockIdx.x;
  int j = 0;
  while (local >= J.cnt[j]) { local -= J.cnt[j]; ++j; }
  int nbx = J.N[j] >> 5, nby = J.K[j] >> 5;
  int z   = local / (nbx * nby);
  int rem = local - z * nbx * nby;
  int by = rem / nbx, bx = rem - by * nbx;
  const float* src = J.src[j] + (long long)z * J.ss[j];
  u16* dst = J.dst[j] + (long long)z * J.ds[j];
  int K = J.K[j], Nsrc = J.Nsrc[j];
  int tx = threadIdx.x, ty = threadIdx.y;
  int n0 = bx * 32, k0 = by * 32;
#pragma unroll
  for (int i = 0; i < 4; ++i){
    float v = 0.f;
    if (n0 + tx < Nsrc) v = src[(size_t)(k0 + ty + i*8) * Nsrc + n0 + tx];
    tile[ty + i*8][tx] = v;
  }
  __syncthreads();
#pragma unroll
  for (int i = 0; i < 4; ++i)
    dst[(size_t)(n0 + ty + i*8) * K + k0 + tx] = f2bf(tile[tx][ty + i*8]);
}

// ---------------------------------------------------------------------------
// Patch extraction: x (B,3,224,224) f32 -> patches (B*196, 768) bf16
// ---------------------------------------------------------------------------
__global__ __launch_bounds__(256) void patch_extract(const float* __restrict__ x,
                                                     u16* __restrict__ patches)
{
  int r = blockIdx.x;
  int b = r / NP_, p = r % NP_;
  int gy = p / 14, gx = p % 14;
  int t = threadIdx.x;
  int py = t >> 4, px = t & 15;
#pragma unroll
  for (int c = 0; c < 3; ++c){
    float v = x[(((size_t)b*3 + c)*224 + gy*16 + py)*224 + gx*16 + px];
    patches[(size_t)r*768 + c*256 + t] = f2bf(v);
  }
}

// ---------------------------------------------------------------------------
// GEMM: C(M,N) = A(M,K)bf16 * Bt(N,K)bf16  (+bias)  [r9 structure, r12 swizzle]
// BMxBN tile, BK=32, NW waves (NW=8: 4x2 of (BM/4)x(BN/2); NW=4: 2x2),
// 16x16x32 MFMA. Ring-2 LDS, depth-1 counted-vmcnt prefetch, K-loop x2.
// LDS swizzle: 16B-chunk p of row r holds source chunk p^((r>>1)&3).
// MODE 0: bf16 = acc+bias ; MODE 2: gelu(acc+bias) bf16 ;
// MODE 3: f32 store, c<N guard (head) ; MODE 4: bf16 slice kz*sstride.
// ---------------------------------------------------------------------------
template<int MODE, int BM, int BN, int KS, int NW>
__global__ __launch_bounds__(NW*64) void gemm_k(const u16* __restrict__ A,
                                                const u16* __restrict__ Bt,
                                                const float* __restrict__ bias,
                                                u16* __restrict__ outb,
                                                float* __restrict__ outf,
                                                int N, int K, int nbx, size_t sstride)
{
  constexpr int WAVES_M = (NW == 8) ? 4 : 2;
  constexpr int WM = BM / WAVES_M;
  constexpr int WN = BN / 2;
  constexpr int MI = WM / 16;
  constexpr int NJ = WN / 16;
  constexpr int CA = BM / (16 * NW);
  constexpr int CB = BN / (16 * NW);
  constexpr int L  = CA + CB;
  __shared__ u16 lds[2*(BM+BN)*32];
  u16* As = lds;
  u16* Bs = lds + 2*BM*32;
  int tid = threadIdx.x;
  int w = tid >> 6, lane = tid & 63;

  int nwg = gridDim.x;
  int q = nwg >> 3, r = nwg & 7;
  int xcd = blockIdx.x & 7, slot = blockIdx.x >> 3;
  int wgid = (xcd < r ? xcd*(q+1) : r*(q+1) + (xcd - r)*q) + slot;
  int m0 = (wgid / nbx) * BM;
  int n0 = (wgid % nbx) * BN;
  int kz = (KS > 1) ? blockIdx.y : 0;
  int Kl = K / KS;
  int koff = kz * Kl;
  int wr = w >> 1, wc = w & 1;

  f32x4 acc[MI][NJ];
#pragma unroll
  for (int i = 0; i < MI; ++i)
#pragma unroll
    for (int j = 0; j < NJ; ++j) acc[i][j] = (f32x4){0.f,0.f,0.f,0.f};

  int srow = lane >> 2;
  int skc  = ((lane & 3) ^ ((lane >> 3) & 3)) * 8;
  const u16* Ag = A  + (size_t)(m0 + w*16 + srow) * K + koff + skc;
  const u16* Bg = Bt + (size_t)(n0 + w*16 + srow) * K + koff + skc;

  int fr  = lane & 15;
  int fsw = ((lane >> 4) ^ ((lane >> 1) & 3)) << 3;

  auto stage = [&](int bi, int kt){
    u16* Ad = As + bi*(BM*32) + (w*16)*32;
    u16* Bd = Bs + bi*(BN*32) + (w*16)*32;
#pragma unroll
    for (int c = 0; c < CA; ++c)
      GLOAD_LDS16(Ag + (size_t)(c*16*NW)*K + kt, Ad + c*16*NW*32);
#pragma unroll
    for (int c = 0; c < CB; ++c)
      GLOAD_LDS16(Bg + (size_t)(c*16*NW)*K + kt, Bd + c*16*NW*32);
  };
  auto compute = [&](int bi){
    const u16* Ab = As + bi*(BM*32);
    const u16* Bb = Bs + bi*(BN*32);
    short8 af[MI], bfr[NJ];
#pragma unroll
    for (int i = 0; i < MI; ++i)
      af[i]  = *(const short8*)&Ab[(wr*WM + i*16 + fr)*32 + fsw];
#pragma unroll
    for (int j = 0; j < NJ; ++j)
      bfr[j] = *(const short8*)&Bb[(wc*WN + j*16 + fr)*32 + fsw];
#pragma unroll
    for (int i = 0; i < MI; ++i)
#pragma unroll
      for (int j = 0; j < NJ; ++j)
        acc[i][j] = MFMA_BF16(af[i], bfr[j], acc[i][j]);
  };

#define WAIT_L()  do { \
    if constexpr (L == 2)      asm volatile("s_waitcnt vmcnt(2)" ::: "memory"); \
    else if constexpr (L == 3) asm volatile("s_waitcnt vmcnt(3)" ::: "memory"); \
    else                       asm volatile("s_waitcnt vmcnt(4)" ::: "memory"); \
  } while (0)

  int nk = Kl >> 5;
  stage(0, 0);
  for (int t = 0; t < nk; t += 2){
    stage(1, (t + 1) * 32);
    __builtin_amdgcn_sched_barrier(0);
    WAIT_L();
    __builtin_amdgcn_s_barrier();
    asm volatile("" ::: "memory");
    compute(0);
    __builtin_amdgcn_sched_barrier(0);
    __builtin_amdgcn_s_barrier();
    if (t + 2 < nk){
      stage(0, (t + 2) * 32);
      __builtin_amdgcn_sched_barrier(0);
      WAIT_L();
    } else {
      __builtin_amdgcn_sched_barrier(0);
      asm volatile("s_waitcnt vmcnt(0)" ::: "memory");
    }
    __builtin_amdgcn_s_barrier();
    asm volatile("" ::: "memory");
    compute(1);
    __builtin_amdgcn_sched_barrier(0);
    __builtin_amdgcn_s_barrier();
  }
#undef WAIT_L

  int cr = (lane >> 4) << 2;
  int cc = lane & 15;

  if constexpr (MODE == 3){
#pragma unroll
    for (int j = 0; j < NJ; ++j){
      int c = n0 + wc*WN + j*16 + cc;
      float bv = bias ? bias[c] : 0.f;
#pragma unroll
      for (int i = 0; i < MI; ++i){
        int rbase = m0 + wr*WM + i*16 + cr;
#pragma unroll
        for (int e = 0; e < 4; ++e){
          float v = acc[i][j][e] + bv;
          if (c < N) outf[(size_t)(rbase + e) * N + c] = v;
        }
      }
    }
  } else {
    constexpr int PITCH = WN + 8;
    u16* Cs = lds + w * (16 * PITCH);
    u16* outp = (MODE == 4) ? outb + (size_t)kz * sstride : outb;
    int lr0 = lane >> 3;
    int lc  = lane & 7;
#pragma unroll
    for (int i = 0; i < MI; ++i){
#pragma unroll
      for (int j = 0; j < NJ; ++j){
        int c = n0 + wc*WN + j*16 + cc;
        float bv = (bias && kz == 0) ? bias[c] : 0.f;
#pragma unroll
        for (int e = 0; e < 4; ++e){
          float v = acc[i][j][e] + bv;
          if (MODE == 2) v = gelu_f(v);
          Cs[(cr + e) * PITCH + j*16 + cc] = f2bf(v);
        }
      }
#pragma unroll
      for (int p = 0; p < 2; ++p){
        int lr = p*8 + lr0;
        short8 val = *(const short8*)&Cs[lr * PITCH + lc*8];
        size_t gm = (size_t)(m0 + wr*WM + i*16 + lr);
        *(short8*)&outp[gm * N + n0 + wc*WN + lc*8] = val;
      }
    }
  }
}

// ---------------------------------------------------------------------------
// LayerNorm rows (plain): in f32 (rows,384) stride rstride -> out bf16
// ---------------------------------------------------------------------------
__global__ __launch_bounds__(256) void ln_rows(const float* __restrict__ in,
                                               const float* __restrict__ gw,
                                               const float* __restrict__ gb,
                                               u16* __restrict__ out, int rows,
                                               size_t rstride)
{
  int m = blockIdx.x * 4 + (threadIdx.x >> 6);
  int lane = threadIdx.x & 63;
  if (m >= rows) return;
  const float* r = in + (size_t)m * rstride;
  float4 v0 = *(const float4*)(r + lane*4);
  float2 v1 = *(const float2*)(r + 256 + lane*2);
  float sum = v0.x+v0.y+v0.z+v0.w+v1.x+v1.y;
  float sq  = v0.x*v0.x+v0.y*v0.y+v0.z*v0.z+v0.w*v0.w+v1.x*v1.x+v1.y*v1.y;
#pragma unroll
  for (int d = 1; d < 64; d <<= 1){ sum += __shfl_xor(sum, d); sq += __shfl_xor(sq, d); }
  float mean = sum * (1.f/D_);
  float rs = rsqrtf(sq*(1.f/D_) - mean*mean + 1e-5f);
  float4 w0 = *(const float4*)(gw + lane*4);
  float2 w1 = *(const float2*)(gw + 256 + lane*2);
  float4 b0 = *(const float4*)(gb + lane*4);
  float2 b1v= *(const float2*)(gb + 256 + lane*2);
  u16x4 o4 = { f2bf((v0.x-mean)*rs*w0.x + b0.x), f2bf((v0.y-mean)*rs*w0.y + b0.y),
               f2bf((v0.z-mean)*rs*w0.z + b0.z), f2bf((v0.w-mean)*rs*w0.w + b0.w) };
  u16x2 o2 = { f2bf((v1.x-mean)*rs*w1.x + b1v.x), f2bf((v1.y-mean)*rs*w1.y + b1v.y) };
  *(u16x4*)(out + (size_t)m*D_ + lane*4) = o4;
  *(u16x2*)(out + (size_t)m*D_ + 256 + lane*2) = o2;
}

// ---------------------------------------------------------------------------
// LayerNorm + slice-reduce: h' = in + s0 + s1 (bf16 slices); out = LN(h');
// ---------------------------------------------------------------------------
__global__ __launch_bounds__(256) void ln_rows_add(const float* __restrict__ in,
                                                   const u16* __restrict__ s0,
                                                   const u16* __restrict__ s1,
                                                   const float* __restrict__ gw,
                                                   const float* __restrict__ gb,
                                                   u16* __restrict__ out,
                                                   float* __restrict__ hout,
                                                   int rows, size_t rstride)
{
  int m = blockIdx.x * 4 + (threadIdx.x >> 6);
  int lane = threadIdx.x & 63;
  if (m >= rows) return;
  const float* r = in + (size_t)m * rstride;
  const u16* p0 = s0 + (size_t)m * rstride;
  const u16* p1 = s1 + (size_t)m * rstride;
  float4 v0 = *(const float4*)(r + lane*4);
  float2 v1 = *(const float2*)(r + 256 + lane*2);
  u16x4 a0 = *(const u16x4*)(p0 + lane*4);
  u16x2 a1 = *(const u16x2*)(p0 + 256 + lane*2);
  u16x4 c0 = *(const u16x4*)(p1 + lane*4);
  u16x2 c1 = *(const u16x2*)(p1 + 256 + lane*2);
  float x0 = v0.x + bf2f(a0.x) + bf2f(c0.x);
  float x1 = v0.y + bf2f(a0.y) + bf2f(c0.y);
  float x2 = v0.z + bf2f(a0.z) + bf2f(c0.z);
  float x3 = v0.w + bf2f(a0.w) + bf2f(c0.w);
  float x4 = v1.x + bf2f(a1.x) + bf2f(c1.x);
  float x5 = v1.y + bf2f(a1.y) + bf2f(c1.y);
  float sum = x0+x1+x2+x3+x4+x5;
  float sq  = x0*x0+x1*x1+x2*x2+x3*x3+x4*x4+x5*x5;
#pragma unroll
  for (int d = 1; d < 64; d <<= 1){ sum += __shfl_xor(sum, d); sq += __shfl_xor(sq, d); }
  float mean = sum * (1.f/D_);
  float rs = rsqrtf(sq*(1.f/D_) - mean*mean + 1e-5f);
  float4 w0 = *(const float4*)(gw + lane*4);
  float2 w1 = *(const float2*)(gw + 256 + lane*2);
  float4 b0 = *(const float4*)(gb + lane*4);
  float2 b1v= *(const float2*)(gb + 256 + lane*2);
  u16x4 o4 = { f2bf((x0-mean)*rs*w0.x + b0.x), f2bf((x1-mean)*rs*w0.y + b0.y),
               f2bf((x2-mean)*rs*w0.z + b0.z), f2bf((x3-mean)*rs*w0.w + b0.w) };
  u16x2 o2 = { f2bf((x4-mean)*rs*w1.x + b1v.x), f2bf((x5-mean)*rs*w1.y + b1v.y) };
  *(u16x4*)(out + (size_t)m*D_ + lane*4) = o4;
  *(u16x2*)(out + (size_t)m*D_ + 256 + lane*2) = o2;
  if (hout){
    float* ho = hout + (size_t)m * rstride;
    float4 h0 = {x0,x1,x2,x3};
    float2 h1 = {x4,x5};
    *(float4*)(ho + lane*4) = h0;
    *(float2*)(ho + 256 + lane*2) = h1;
  }
}

// ---------------------------------------------------------------------------
// Assemble h (M_PAD,384) f32
// ---------------------------------------------------------------------------
__global__ __launch_bounds__(256) void assemble_h(const u16* __restrict__ pe,
                                                  const float* __restrict__ gw,
                                                  const float* __restrict__ gb,
                                                  const float* __restrict__ pos,
                                                  const float* __restrict__ cls,
                                                  float* __restrict__ h)
{
  int m = blockIdx.x * 4 + (threadIdx.x >> 6);
  int lane = threadIdx.x & 63;
  if (m >= M_PAD) return;
  float* ho = h + (size_t)m * D_;
  if (m >= M_REAL){
    float4 z = {0.f,0.f,0.f,0.f};
    *(float4*)(ho + lane*4) = z;
    float2 z2 = {0.f,0.f};
    *(float2*)(ho + 256 + lane*2) = z2;
    return;
  }
  int b = m / NT_, t = m % NT_;
  const float* pr = pos + (size_t)t * D_;
  float4 p0 = *(const float4*)(pr + lane*4);
  float2 p1 = *(const float2*)(pr + 256 + lane*2);
  if (t == 0){
    float4 c0 = *(const float4*)(cls + lane*4);
    float2 c1 = *(const float2*)(cls + 256 + lane*2);
    float4 r0 = {c0.x+p0.x, c0.y+p0.y, c0.z+p0.z, c0.w+p0.w};
    float2 r1 = {c1.x+p1.x, c1.y+p1.y};
    *(float4*)(ho + lane*4) = r0;
    *(float2*)(ho + 256 + lane*2) = r1;
  } else {
    const u16* per = pe + (size_t)(b*NP_ + (t-1)) * D_;
    u16x4 a0 = *(const u16x4*)(per + lane*4);
    u16x2 a1 = *(const u16x2*)(per + 256 + lane*2);
    float x0=bf2f(a0.x), x1=bf2f(a0.y), x2=bf2f(a0.z), x3=bf2f(a0.w), x4=bf2f(a1.x), x5=bf2f(a1.y);
    float sum = x0+x1+x2+x3+x4+x5;
    float sq  = x0*x0+x1*x1+x2*x2+x3*x3+x4*x4+x5*x5;
#pragma unroll
    for (int d = 1; d < 64; d <<= 1){ sum += __shfl_xor(sum, d); sq += __shfl_xor(sq, d); }
    float mean = sum * (1.f/D_);
    float rs = rsqrtf(sq*(1.f/D_) - mean*mean + 1e-5f);
    float4 w0 = *(const float4*)(gw + lane*4);
    float2 w1 = *(const float2*)(gw + 256 + lane*2);
    float4 b0 = *(const float4*)(gb + lane*4);
    float2 b1v= *(const float2*)(gb + 256 + lane*2);
    float4 r0 = { (x0-mean)*rs*w0.x + b0.x + p0.x, (x1-mean)*rs*w0.y + b0.y + p0.y,
                  (x2-mean)*rs*w0.z + b0.z + p0.z, (x3-mean)*rs*w0.w + b0.w + p0.w };
    float2 r1 = { (x4-mean)*rs*w1.x + b1v.x + p1.x, (x5-mean)*rs*w1.y + b1v.y + p1.y };
    *(float4*)(ho + lane*4) = r0;
    *(float2*)(ho + 256 + lane*2) = r1;
  }
}

// ---------------------------------------------------------------------------
// Fused attention over packed qkv (M,1152): [q(384) | k(384) | v(384)].
// One block per (b, head). 8 waves (512 thr); wave owns qt = w, w+8.
// ---------------------------------------------------------------------------
__global__ __launch_bounds__(512) void attn_k(const u16* __restrict__ qkv,
                                              u16* __restrict__ o)
{
  __shared__ u16 Ks[208*72];
  __shared__ u16 Vt[64*232];
  __shared__ u16 Ps[8][16*40];
  int bh = blockIdx.x;
  int b = bh / NH, hh = bh % NH;
  int tid = threadIdx.x, w = tid >> 6, lane = tid & 63;
  const u16* kbase = qkv + (size_t)b*NT_*1152 + 384 + hh*64;
  const u16* vbase = kbase + 384;

  int jr = tid >> 3, col = (tid & 7) * 8;   // jr 0..63
#pragma unroll
  for (int it = 0; it < 4; ++it){            // stage K rows, zero pads
    int j = it*64 + jr;
    if (j < 208){
      uint4 val = {0u,0u,0u,0u};
      if (j < 197) val = *(const uint4*)(kbase + (size_t)j*1152 + col);
      *(uint4*)&Ks[j*72 + col] = val;
    }
  }
#pragma unroll
  for (int it = 0; it < 4; ++it){            // stage V^T, zero cols >=197
    int j = it*64 + jr;                      // need 0..223
    if (j < 224){
      union { uint4 v; u16 s[8]; } u;
      u.v.x = 0u; u.v.y = 0u; u.v.z = 0u; u.v.w = 0u;
      if (j < 197) u.v = *(const uint4*)(vbase + (size_t)j*1152 + col);
#pragma unroll
      for (int e = 0; e < 8; ++e) Vt[(size_t)(col+e)*232 + j] = u.s[e];
    }
  }
  __syncthreads();

  u16* myP = Ps[w];
  int fr = lane & 15, fk = lane >> 4;

  for (int qt = w; qt < 13; qt += 8){
    const u16* qrow = qkv + (size_t)(b*NT_ + qt*16 + fr)*1152 + hh*64 + fk*8;
    short8 aq0 = *(const short8*)qrow;
    short8 aq1 = *(const short8*)(qrow + 32);

    f32x4 s[13];
#pragma unroll
    for (int jt = 0; jt < 13; ++jt){
      const u16* kr = &Ks[(jt*16 + fr)*72 + fk*8];
      short8 bk0 = *(const short8*)kr;
      short8 bk1 = *(const short8*)(kr + 32);
      f32x4 z = {0.f,0.f,0.f,0.f};
      z = MFMA_BF16(aq0, bk0, z);
      z = MFMA_BF16(aq1, bk1, z);
      s[jt] = z;
    }

#pragma unroll
    for (int e = 0; e < 4; ++e){
      float mx = -1e30f;
#pragma unroll
      for (int jt = 0; jt < 13; ++jt){
        int cj = jt*16 + fr;
        float v = (cj < NT_) ? s[jt][e]*0.125f : -1e30f;
        s[jt][e] = v;
        mx = fmaxf(mx, v);
      }
#pragma unroll
      for (int d = 1; d < 16; d <<= 1) mx = fmaxf(mx, __shfl_xor(mx, d));
      float su = 0.f;
#pragma unroll
      for (int jt = 0; jt < 13; ++jt){
        float p = __expf(s[jt][e] - mx);
        s[jt][e] = p; su += p;
      }
#pragma unroll
      for (int d = 1; d < 16; d <<= 1) su += __shfl_xor(su, d);
      float ri = 1.f / su;
#pragma unroll
      for (int jt = 0; jt < 13; ++jt) s[jt][e] *= ri;
    }

    f32x4 oacc[4];
#pragma unroll
    for (int dt = 0; dt < 4; ++dt) oacc[dt] = (f32x4){0.f,0.f,0.f,0.f};
#pragma unroll
    for (int jc = 0; jc < 7; ++jc){
#pragma unroll
      for (int jtl = 0; jtl < 2; ++jtl){
        int jt = jc*2 + jtl;
#pragma unroll
        for (int e = 0; e < 4; ++e){
          u16 pv = 0;
          if (jt < 13) pv = f2bf(s[jt][e]);
          myP[(fk*4 + e)*40 + jtl*16 + fr] = pv;
        }
      }
      asm volatile("s_waitcnt lgkmcnt(0)" ::: "memory");
      short8 pa = *(const short8*)&myP[fr*40 + fk*8];
#pragma unroll
      for (int dt = 0; dt < 4; ++dt){
        short8 bv = *(const short8*)&Vt[(size_t)(dt*16 + fr)*232 + jc*32 + fk*8];
        oacc[dt] = MFMA_BF16(pa, bv, oacc[dt]);
      }
    }

#pragma unroll
    for (int dt = 0; dt < 4; ++dt)
#pragma unroll
      for (int e = 0; e < 4; ++e){
        int t = qt*16 + fk*4 + e;
        if (t < NT_)
          o[(size_t)(b*NT_ + t)*384 + hh*64 + dt*16 + fr] = f2bf(oacc[dt][e]);
      }
  }
}

// ---------------------------------------------------------------------------
extern "C" void kernel_launch(void* const* d_in, const int* in_sizes, int n_in,
                              void* d_out, int out_size, void* d_ws, size_t ws_size,
                              hipStream_t stream)
{
  (void)in_sizes; (void)n_in; (void)out_size; (void)ws_size;
  const float* x_in    = (const float*)d_in[0];
  const float* W_patch = (const float*)d_in[1];
  const float* b_patch = (const float*)d_in[2];
  const float* ln0_w   = (const float*)d_in[3];
  const float* ln0_b   = (const float*)d_in[4];
  const float* pos_emb = (const float*)d_in[5];
  const float* cls_tok = (const float*)d_in[6];
  const float* ln1_w   = (const float*)d_in[7];
  const float* ln1_b   = (const float*)d_in[8];
  const float* Wq      = (const float*)d_in[9];
  const float* Wkv     = (const float*)d_in[10];
  const float* Wo      = (const float*)d_in[11];
  const float* bo      = (const float*)d_in[12];
  const float* ln2_w   = (const float*)d_in[13];
  const float* ln2_b   = (const float*)d_in[14];
  const float* W1      = (const float*)d_in[15];
  const float* b1      = (const float*)d_in[16];
  const float* W2      = (const float*)d_in[17];
  const float* b2      = (const float*)d_in[18];
  const float* lnf_w   = (const float*)d_in[19];
  const float* lnf_b   = (const float*)d_in[20];
  const float* Whead   = (const float*)d_in[21];
  const float* bhead   = (const float*)d_in[22];

  char* ws = (char*)d_ws;
  size_t off = 0;
  auto nxt = [&](size_t bytes)->char* {
    char* p = ws + off;
    off += (bytes + 255) & ~(size_t)255;
    return p;
  };
  u16*   g_buf   = (u16*)  nxt((size_t)M_PAD * DFF_ * 2);   // also: patches
  float* hbuf    = (float*)nxt((size_t)M_PAD * D_ * 4);
  u16*   abuf    = (u16*)  nxt((size_t)M_PAD * D_ * 2);     // also: patch-embed out
  u16*   qkvbuf  = (u16*)  nxt((size_t)M_PAD * 1152 * 2);
  u16*   obuf    = (u16*)  nxt((size_t)M_PAD * D_ * 2);
  u16*   sbuf    = (u16*)  nxt((size_t)2 * M_PAD * D_ * 2); // split-K slices
  u16*   lncls   = (u16*)  nxt((size_t)B_ * D_ * 2);
  u16*   whT     = (u16*)  nxt((size_t)1024 * D_ * 2);
  u16*   wT      = (u16*)  nxt((size_t)21528576 * 2);

  const size_t SS = (size_t)M_PAD * D_;
  u16* patches = g_buf;
  u16* pebuf   = abuf;
  u16* wpT   = wT;
  u16* wqkvT = wpT   + 294912;
  u16* woT   = wqkvT + 12*442368;
  u16* w1T   = woT   + 12*147456;
  u16* w2T   = w1T   + 12*589824;

  TJobs J;
  auto setj = [&](int i, const float* s, u16* d, int N, int K, int Nsrc,
                  long long ss, long long ds, int nz){
    J.src[i]=s; J.dst[i]=d; J.N[i]=N; J.K[i]=K; J.Nsrc[i]=Nsrc;
    J.ss[i]=ss; J.ds[i]=ds; J.cnt[i]=(N/32)*(K/32)*nz;
  };
  setj(0, W_patch, wpT,             384,  768,  384, 0, 0, 1);
  setj(1, Wq,      wqkvT,           384,  384,  384, 384LL*384,  1152LL*384, 12);
  setj(2, Wkv,     wqkvT + 384*384, 768,  384,  768, 384LL*768,  1152LL*384, 12);
  setj(3, Wo,      woT,             384,  384,  384, 384LL*384,  384LL*384,  12);
  setj(4, W1,      w1T,             1536, 384, 1536, 384LL*1536, 384LL*1536, 12);
  setj(5, W2,      w2T,             384, 1536,  384, 1536LL*384, 1536LL*384, 12);
  setj(6, Whead,   whT,             1024, 384, 1000, 0, 0, 1);
  int tblocks = 0;
  for (int i = 0; i < 7; ++i) tblocks += J.cnt[i];
  transpose_all<<<tblocks, dim3(32,8), 0, stream>>>(J);

  patch_extract<<<M_PATCH, 256, 0, stream>>>(x_in, patches);
  gemm_k<0,128,128,1,8><<<3*(M_PATCH/128), 512, 0, stream>>>(patches, wpT, b_patch, pebuf, nullptr, 384, 768, 3, 0);
  assemble_h<<<M_PAD/4, 256, 0, stream>>>(pebuf, ln0_w, ln0_b, pos_emb, cls_tok, hbuf);

  for (int d = 0; d < DEPTH_; ++d){
    if (d == 0)
      ln_rows<<<M_PAD/4, 256, 0, stream>>>(hbuf, ln1_w, ln1_b, abuf, M_PAD, D_);
    else
      ln_rows_add<<<M_PAD/4, 256, 0, stream>>>(hbuf, sbuf, sbuf + SS,
                                               ln1_w + d*384, ln1_b + d*384,
                                               abuf, hbuf, M_PAD, D_);
    gemm_k<0,128,128,1,8><<<9*(M_PAD/128), 512, 0, stream>>>(abuf, wqkvT + (size_t)d*442368, nullptr, qkvbuf, nullptr, 1152, 384, 9, 0);
    attn_k<<<B_*NH, 512, 0, stream>>>(qkvbuf, obuf);
    gemm_k<4,128,128,2,8><<<dim3(3*(M_PAD/128), 2), 512, 0, stream>>>(obuf, woT + (size_t)d*147456, bo + d*384, sbuf, nullptr, 384, 384, 3, SS);
    ln_rows_add<<<M_PAD/4, 256, 0, stream>>>(hbuf, sbuf, sbuf + SS,
                                             ln2_w + d*384, ln2_b + d*384,
                                             abuf, hbuf, M_PAD, D_);
    gemm_k<2,128,128,1,8><<<12*(M_PAD/128), 512, 0, stream>>>(abuf, w1T + (size_t)d*589824, b1 + d*1536, g_buf, nullptr, 1536, 384, 12, 0);
    gemm_k<4,128,128,2,8><<<dim3(3*(M_PAD/128), 2), 512, 0, stream>>>(g_buf, w2T + (size_t)d*589824, b2 + d*384, sbuf, nullptr, 384, 1536, 3, SS);
  }

  ln_rows_add<<<B_/4, 256, 0, stream>>>(hbuf, sbuf, sbuf + SS,
                                        lnf_w, lnf_b, lncls, nullptr,
                                        B_, (size_t)NT_*D_);
  gemm_k<3,64,64,1,4><<<16, 256, 0, stream>>>(lncls, whT, bhead, nullptr, (float*)d_out, 1000, 384, 16, 0);
}

// Round 15
// 1679.659 us; speedup vs baseline: 2.3915x; 1.0413x over previous
//
#include <hip/hip_runtime.h>

// ---------------------------------------------------------------------------
// ViT-S/16 forward, bf16 MFMA everywhere, fp16 residual stream.
// Round 15: residual h stored as fp16 (was f32) — ln_rows_add moved 68MB per
// dispatch (x23), dominated by the f32 h read+write. fp16 halves that spine
// (48.6MB) with ~4x less rounding error than bf16 (10-bit mantissa; one RNE
// rounding per layer update). GEMM/attention unchanged from r14 (1749us).
// ---------------------------------------------------------------------------

typedef unsigned short u16;
typedef __attribute__((ext_vector_type(8))) short short8;   // 8 bf16 MFMA A/B frag
typedef __attribute__((ext_vector_type(4))) float f32x4;    // MFMA C/D frag
typedef __attribute__((ext_vector_type(4))) unsigned short u16x4;
typedef __attribute__((ext_vector_type(2))) unsigned short u16x2;

#define D_      384
#define NH      6
#define DEPTH_  12
#define NP_     196
#define NT_     197
#define B_      64
#define DFF_    1536
#define M_REAL  (B_*NT_)      // 12608
#define M_PAD   12672         // 99*128
#define M_PATCH (B_*NP_)      // 12544 = 98*128

__device__ __forceinline__ float bf2f(u16 u){
  unsigned int i = ((unsigned int)u) << 16;
  return __builtin_bit_cast(float, i);
}
__device__ __forceinline__ u16 f2bf(float f){
  unsigned int i = __builtin_bit_cast(unsigned int, f);
  i = (i + 0x7FFFu + ((i >> 16) & 1u)) >> 16;   // RNE
  return (u16)i;
}
__device__ __forceinline__ u16 f2h(float f){
  _Float16 h = (_Float16)f;                     // v_cvt_f16_f32 (RNE)
  return __builtin_bit_cast(unsigned short, h);
}
__device__ __forceinline__ float h2f(u16 u){
  return (float)__builtin_bit_cast(_Float16, u);
}
__device__ __forceinline__ float gelu_f(float x){
  float t = x * (1.595769122f + 0.0713548162726f * x * x);
  return x / (1.f + __expf(-t));
}

#define GLOAD_LDS16(g, l) __builtin_amdgcn_global_load_lds( \
    (const __attribute__((address_space(1))) void*)(g),      \
    (__attribute__((address_space(3))) void*)(l), 16, 0, 0)

#define MFMA_BF16(a, b, c) __builtin_amdgcn_mfma_f32_16x16x32_bf16((a), (b), (c), 0, 0, 0)

// ---------------------------------------------------------------------------
// Merged weight transpose: 7 jobs. src (K,Nsrc) f32 -> (N,K) bf16
// ---------------------------------------------------------------------------
struct TJobs {
  const float* src[7];
  u16*         dst[7];
  int          N[7], K[7], Nsrc[7];
  long long    ss[7], ds[7];
  int          cnt[7];
};

__global__ __launch_bounds__(256) void transpose_all(TJobs J)
{
  __shared__ float tile[32][33];
  int local = blockIdx.x;
  int j = 0;
  while (local >= J.cnt[j]) { local -= J.cnt[j]; ++j; }
  int nbx = J.N[j] >> 5, nby = J.K[j] >> 5;
  int z   = local / (nbx * nby);
  int rem = local - z * nbx * nby;
  int by = rem / nbx, bx = rem - by * nbx;
  const float* src = J.src[j] + (long long)z * J.ss[j];
  u16* dst = J.dst[j] + (long long)z * J.ds[j];
  int K = J.K[j], Nsrc = J.Nsrc[j];
  int tx = threadIdx.x, ty = threadIdx.y;
  int n0 = bx * 32, k0 = by * 32;
#pragma unroll
  for (int i = 0; i < 4; ++i){
    float v = 0.f;
    if (n0 + tx < Nsrc) v = src[(size_t)(k0 + ty + i*8) * Nsrc + n0 + tx];
    tile[ty + i*8][tx] = v;
  }
  __syncthreads();
#pragma unroll
  for (int i = 0; i < 4; ++i)
    dst[(size_t)(n0 + ty + i*8) * K + k0 + tx] = f2bf(tile[tx][ty + i*8]);
}

// ---------------------------------------------------------------------------
// Patch extraction: x (B,3,224,224) f32 -> patches (B*196, 768) bf16
// ---------------------------------------------------------------------------
__global__ __launch_bounds__(256) void patch_extract(const float* __restrict__ x,
                                                     u16* __restrict__ patches)
{
  int r = blockIdx.x;
  int b = r / NP_, p = r % NP_;
  int gy = p / 14, gx = p % 14;
  int t = threadIdx.x;
  int py = t >> 4, px = t & 15;
#pragma unroll
  for (int c = 0; c < 3; ++c){
    float v = x[(((size_t)b*3 + c)*224 + gy*16 + py)*224 + gx*16 + px];
    patches[(size_t)r*768 + c*256 + t] = f2bf(v);
  }
}

// ---------------------------------------------------------------------------
// GEMM: C(M,N) = A(M,K)bf16 * Bt(N,K)bf16  (+bias)  [r9 structure, r12 swizzle]
// BMxBN tile, BK=32, NW waves, 16x16x32 MFMA. Ring-2 LDS, depth-1 counted-
// vmcnt prefetch, K-loop x2. MODE 0: bf16 = acc+bias ; MODE 2: gelu bf16 ;
// MODE 3: f32 store, c<N guard (head) ; MODE 4: bf16 slice kz*sstride.
// ---------------------------------------------------------------------------
template<int MODE, int BM, int BN, int KS, int NW>
__global__ __launch_bounds__(NW*64) void gemm_k(const u16* __restrict__ A,
                                                const u16* __restrict__ Bt,
                                                const float* __restrict__ bias,
                                                u16* __restrict__ outb,
                                                float* __restrict__ outf,
                                                int N, int K, int nbx, size_t sstride)
{
  constexpr int WAVES_M = (NW == 8) ? 4 : 2;
  constexpr int WM = BM / WAVES_M;
  constexpr int WN = BN / 2;
  constexpr int MI = WM / 16;
  constexpr int NJ = WN / 16;
  constexpr int CA = BM / (16 * NW);
  constexpr int CB = BN / (16 * NW);
  constexpr int L  = CA + CB;
  __shared__ u16 lds[2*(BM+BN)*32];
  u16* As = lds;
  u16* Bs = lds + 2*BM*32;
  int tid = threadIdx.x;
  int w = tid >> 6, lane = tid & 63;

  int nwg = gridDim.x;
  int q = nwg >> 3, r = nwg & 7;
  int xcd = blockIdx.x & 7, slot = blockIdx.x >> 3;
  int wgid = (xcd < r ? xcd*(q+1) : r*(q+1) + (xcd - r)*q) + slot;
  int m0 = (wgid / nbx) * BM;
  int n0 = (wgid % nbx) * BN;
  int kz = (KS > 1) ? blockIdx.y : 0;
  int Kl = K / KS;
  int koff = kz * Kl;
  int wr = w >> 1, wc = w & 1;

  f32x4 acc[MI][NJ];
#pragma unroll
  for (int i = 0; i < MI; ++i)
#pragma unroll
    for (int j = 0; j < NJ; ++j) acc[i][j] = (f32x4){0.f,0.f,0.f,0.f};

  int srow = lane >> 2;
  int skc  = ((lane & 3) ^ ((lane >> 3) & 3)) * 8;
  const u16* Ag = A  + (size_t)(m0 + w*16 + srow) * K + koff + skc;
  const u16* Bg = Bt + (size_t)(n0 + w*16 + srow) * K + koff + skc;

  int fr  = lane & 15;
  int fsw = ((lane >> 4) ^ ((lane >> 1) & 3)) << 3;

  auto stage = [&](int bi, int kt){
    u16* Ad = As + bi*(BM*32) + (w*16)*32;
    u16* Bd = Bs + bi*(BN*32) + (w*16)*32;
#pragma unroll
    for (int c = 0; c < CA; ++c)
      GLOAD_LDS16(Ag + (size_t)(c*16*NW)*K + kt, Ad + c*16*NW*32);
#pragma unroll
    for (int c = 0; c < CB; ++c)
      GLOAD_LDS16(Bg + (size_t)(c*16*NW)*K + kt, Bd + c*16*NW*32);
  };
  auto compute = [&](int bi){
    const u16* Ab = As + bi*(BM*32);
    const u16* Bb = Bs + bi*(BN*32);
    short8 af[MI], bfr[NJ];
#pragma unroll
    for (int i = 0; i < MI; ++i)
      af[i]  = *(const short8*)&Ab[(wr*WM + i*16 + fr)*32 + fsw];
#pragma unroll
    for (int j = 0; j < NJ; ++j)
      bfr[j] = *(const short8*)&Bb[(wc*WN + j*16 + fr)*32 + fsw];
#pragma unroll
    for (int i = 0; i < MI; ++i)
#pragma unroll
      for (int j = 0; j < NJ; ++j)
        acc[i][j] = MFMA_BF16(af[i], bfr[j], acc[i][j]);
  };

#define WAIT_L()  do { \
    if constexpr (L == 2)      asm volatile("s_waitcnt vmcnt(2)" ::: "memory"); \
    else if constexpr (L == 3) asm volatile("s_waitcnt vmcnt(3)" ::: "memory"); \
    else                       asm volatile("s_waitcnt vmcnt(4)" ::: "memory"); \
  } while (0)

  int nk = Kl >> 5;
  stage(0, 0);
  for (int t = 0; t < nk; t += 2){
    stage(1, (t + 1) * 32);
    __builtin_amdgcn_sched_barrier(0);
    WAIT_L();
    __builtin_amdgcn_s_barrier();
    asm volatile("" ::: "memory");
    compute(0);
    __builtin_amdgcn_sched_barrier(0);
    __builtin_amdgcn_s_barrier();
    if (t + 2 < nk){
      stage(0, (t + 2) * 32);
      __builtin_amdgcn_sched_barrier(0);
      WAIT_L();
    } else {
      __builtin_amdgcn_sched_barrier(0);
      asm volatile("s_waitcnt vmcnt(0)" ::: "memory");
    }
    __builtin_amdgcn_s_barrier();
    asm volatile("" ::: "memory");
    compute(1);
    __builtin_amdgcn_sched_barrier(0);
    __builtin_amdgcn_s_barrier();
  }
#undef WAIT_L

  int cr = (lane >> 4) << 2;
  int cc = lane & 15;

  if constexpr (MODE == 3){
#pragma unroll
    for (int j = 0; j < NJ; ++j){
      int c = n0 + wc*WN + j*16 + cc;
      float bv = bias ? bias[c] : 0.f;
#pragma unroll
      for (int i = 0; i < MI; ++i){
        int rbase = m0 + wr*WM + i*16 + cr;
#pragma unroll
        for (int e = 0; e < 4; ++e){
          float v = acc[i][j][e] + bv;
          if (c < N) outf[(size_t)(rbase + e) * N + c] = v;
        }
      }
    }
  } else {
    constexpr int PITCH = WN + 8;
    u16* Cs = lds + w * (16 * PITCH);
    u16* outp = (MODE == 4) ? outb + (size_t)kz * sstride : outb;
    int lr0 = lane >> 3;
    int lc  = lane & 7;
#pragma unroll
    for (int i = 0; i < MI; ++i){
#pragma unroll
      for (int j = 0; j < NJ; ++j){
        int c = n0 + wc*WN + j*16 + cc;
        float bv = (bias && kz == 0) ? bias[c] : 0.f;
#pragma unroll
        for (int e = 0; e < 4; ++e){
          float v = acc[i][j][e] + bv;
          if (MODE == 2) v = gelu_f(v);
          Cs[(cr + e) * PITCH + j*16 + cc] = f2bf(v);
        }
      }
#pragma unroll
      for (int p = 0; p < 2; ++p){
        int lr = p*8 + lr0;
        short8 val = *(const short8*)&Cs[lr * PITCH + lc*8];
        size_t gm = (size_t)(m0 + wr*WM + i*16 + lr);
        *(short8*)&outp[gm * N + n0 + wc*WN + lc*8] = val;
      }
    }
  }
}

// ---------------------------------------------------------------------------
// LayerNorm rows (plain): in fp16 (rows,384) stride rstride -> out bf16
// ---------------------------------------------------------------------------
__global__ __launch_bounds__(256) void ln_rows(const u16* __restrict__ in,
                                               const float* __restrict__ gw,
                                               const float* __restrict__ gb,
                                               u16* __restrict__ out, int rows,
                                               size_t rstride)
{
  int m = blockIdx.x * 4 + (threadIdx.x >> 6);
  int lane = threadIdx.x & 63;
  if (m >= rows) return;
  const u16* r = in + (size_t)m * rstride;
  u16x4 v0 = *(const u16x4*)(r + lane*4);
  u16x2 v1 = *(const u16x2*)(r + 256 + lane*2);
  float x0=h2f(v0.x), x1=h2f(v0.y), x2=h2f(v0.z), x3=h2f(v0.w), x4=h2f(v1.x), x5=h2f(v1.y);
  float sum = x0+x1+x2+x3+x4+x5;
  float sq  = x0*x0+x1*x1+x2*x2+x3*x3+x4*x4+x5*x5;
#pragma unroll
  for (int d = 1; d < 64; d <<= 1){ sum += __shfl_xor(sum, d); sq += __shfl_xor(sq, d); }
  float mean = sum * (1.f/D_);
  float rs = rsqrtf(sq*(1.f/D_) - mean*mean + 1e-5f);
  float4 w0 = *(const float4*)(gw + lane*4);
  float2 w1 = *(const float2*)(gw + 256 + lane*2);
  float4 b0 = *(const float4*)(gb + lane*4);
  float2 b1v= *(const float2*)(gb + 256 + lane*2);
  u16x4 o4 = { f2bf((x0-mean)*rs*w0.x + b0.x), f2bf((x1-mean)*rs*w0.y + b0.y),
               f2bf((x2-mean)*rs*w0.z + b0.z), f2bf((x3-mean)*rs*w0.w + b0.w) };
  u16x2 o2 = { f2bf((x4-mean)*rs*w1.x + b1v.x), f2bf((x5-mean)*rs*w1.y + b1v.y) };
  *(u16x4*)(out + (size_t)m*D_ + lane*4) = o4;
  *(u16x2*)(out + (size_t)m*D_ + 256 + lane*2) = o2;
}

// ---------------------------------------------------------------------------
// LayerNorm + slice-reduce: h' = in(fp16) + s0 + s1 (bf16); out = LN(h') bf16;
// optionally write h' back (fp16). One wave per row.
// ---------------------------------------------------------------------------
__global__ __launch_bounds__(256) void ln_rows_add(const u16* __restrict__ in,
                                                   const u16* __restrict__ s0,
                                                   const u16* __restrict__ s1,
                                                   const float* __restrict__ gw,
                                                   const float* __restrict__ gb,
                                                   u16* __restrict__ out,
                                                   u16* __restrict__ hout,
                                                   int rows, size_t rstride)
{
  int m = blockIdx.x * 4 + (threadIdx.x >> 6);
  int lane = threadIdx.x & 63;
  if (m >= rows) return;
  const u16* r = in + (size_t)m * rstride;
  const u16* p0 = s0 + (size_t)m * rstride;
  const u16* p1 = s1 + (size_t)m * rstride;
  u16x4 v0 = *(const u16x4*)(r + lane*4);
  u16x2 v1 = *(const u16x2*)(r + 256 + lane*2);
  u16x4 a0 = *(const u16x4*)(p0 + lane*4);
  u16x2 a1 = *(const u16x2*)(p0 + 256 + lane*2);
  u16x4 c0 = *(const u16x4*)(p1 + lane*4);
  u16x2 c1 = *(const u16x2*)(p1 + 256 + lane*2);
  float x0 = h2f(v0.x) + bf2f(a0.x) + bf2f(c0.x);
  float x1 = h2f(v0.y) + bf2f(a0.y) + bf2f(c0.y);
  float x2 = h2f(v0.z) + bf2f(a0.z) + bf2f(c0.z);
  float x3 = h2f(v0.w) + bf2f(a0.w) + bf2f(c0.w);
  float x4 = h2f(v1.x) + bf2f(a1.x) + bf2f(c1.x);
  float x5 = h2f(v1.y) + bf2f(a1.y) + bf2f(c1.y);
  float sum = x0+x1+x2+x3+x4+x5;
  float sq  = x0*x0+x1*x1+x2*x2+x3*x3+x4*x4+x5*x5;
#pragma unroll
  for (int d = 1; d < 64; d <<= 1){ sum += __shfl_xor(sum, d); sq += __shfl_xor(sq, d); }
  float mean = sum * (1.f/D_);
  float rs = rsqrtf(sq*(1.f/D_) - mean*mean + 1e-5f);
  float4 w0 = *(const float4*)(gw + lane*4);
  float2 w1 = *(const float2*)(gw + 256 + lane*2);
  float4 b0 = *(const float4*)(gb + lane*4);
  float2 b1v= *(const float2*)(gb + 256 + lane*2);
  u16x4 o4 = { f2bf((x0-mean)*rs*w0.x + b0.x), f2bf((x1-mean)*rs*w0.y + b0.y),
               f2bf((x2-mean)*rs*w0.z + b0.z), f2bf((x3-mean)*rs*w0.w + b0.w) };
  u16x2 o2 = { f2bf((x4-mean)*rs*w1.x + b1v.x), f2bf((x5-mean)*rs*w1.y + b1v.y) };
  *(u16x4*)(out + (size_t)m*D_ + lane*4) = o4;
  *(u16x2*)(out + (size_t)m*D_ + 256 + lane*2) = o2;
  if (hout){
    u16* ho = hout + (size_t)m * rstride;
    u16x4 h0 = { f2h(x0), f2h(x1), f2h(x2), f2h(x3) };
    u16x2 h1 = { f2h(x4), f2h(x5) };
    *(u16x4*)(ho + lane*4) = h0;
    *(u16x2*)(ho + 256 + lane*2) = h1;
  }
}

// ---------------------------------------------------------------------------
// Assemble h (M_PAD,384) fp16: t==0 -> cls+pos ; t>=1 -> LN0(pe)+pos ; pad->0
// ---------------------------------------------------------------------------
__global__ __launch_bounds__(256) void assemble_h(const u16* __restrict__ pe,
                                                  const float* __restrict__ gw,
                                                  const float* __restrict__ gb,
                                                  const float* __restrict__ pos,
                                                  const float* __restrict__ cls,
                                                  u16* __restrict__ h)
{
  int m = blockIdx.x * 4 + (threadIdx.x >> 6);
  int lane = threadIdx.x & 63;
  if (m >= M_PAD) return;
  u16* ho = h + (size_t)m * D_;
  if (m >= M_REAL){
    u16x4 z4 = {0,0,0,0};
    u16x2 z2 = {0,0};
    *(u16x4*)(ho + lane*4) = z4;
    *(u16x2*)(ho + 256 + lane*2) = z2;
    return;
  }
  int b = m / NT_, t = m % NT_;
  const float* pr = pos + (size_t)t * D_;
  float4 p0 = *(const float4*)(pr + lane*4);
  float2 p1 = *(const float2*)(pr + 256 + lane*2);
  if (t == 0){
    float4 c0 = *(const float4*)(cls + lane*4);
    float2 c1 = *(const float2*)(cls + 256 + lane*2);
    u16x4 r0 = { f2h(c0.x+p0.x), f2h(c0.y+p0.y), f2h(c0.z+p0.z), f2h(c0.w+p0.w) };
    u16x2 r1 = { f2h(c1.x+p1.x), f2h(c1.y+p1.y) };
    *(u16x4*)(ho + lane*4) = r0;
    *(u16x2*)(ho + 256 + lane*2) = r1;
  } else {
    const u16* per = pe + (size_t)(b*NP_ + (t-1)) * D_;
    u16x4 a0 = *(const u16x4*)(per + lane*4);
    u16x2 a1 = *(const u16x2*)(per + 256 + lane*2);
    float x0=bf2f(a0.x), x1=bf2f(a0.y), x2=bf2f(a0.z), x3=bf2f(a0.w), x4=bf2f(a1.x), x5=bf2f(a1.y);
    float sum = x0+x1+x2+x3+x4+x5;
    float sq  = x0*x0+x1*x1+x2*x2+x3*x3+x4*x4+x5*x5;
#pragma unroll
    for (int d = 1; d < 64; d <<= 1){ sum += __shfl_xor(sum, d); sq += __shfl_xor(sq, d); }
    float mean = sum * (1.f/D_);
    float rs = rsqrtf(sq*(1.f/D_) - mean*mean + 1e-5f);
    float4 w0 = *(const float4*)(gw + lane*4);
    float2 w1 = *(const float2*)(gw + 256 + lane*2);
    float4 b0 = *(const float4*)(gb + lane*4);
    float2 b1v= *(const float2*)(gb + 256 + lane*2);
    u16x4 r0 = { f2h((x0-mean)*rs*w0.x + b0.x + p0.x), f2h((x1-mean)*rs*w0.y + b0.y + p0.y),
                 f2h((x2-mean)*rs*w0.z + b0.z + p0.z), f2h((x3-mean)*rs*w0.w + b0.w + p0.w) };
    u16x2 r1 = { f2h((x4-mean)*rs*w1.x + b1v.x + p1.x), f2h((x5-mean)*rs*w1.y + b1v.y + p1.y) };
    *(u16x4*)(ho + lane*4) = r0;
    *(u16x2*)(ho + 256 + lane*2) = r1;
  }
}

// ---------------------------------------------------------------------------
// Fused attention over packed qkv (M,1152): [q(384) | k(384) | v(384)].
// One block per (b, head). 8 waves (512 thr); wave owns qt = w, w+8.
// ---------------------------------------------------------------------------
__global__ __launch_bounds__(512) void attn_k(const u16* __restrict__ qkv,
                                              u16* __restrict__ o)
{
  __shared__ u16 Ks[208*72];
  __shared__ u16 Vt[64*232];
  __shared__ u16 Ps[8][16*40];
  int bh = blockIdx.x;
  int b = bh / NH, hh = bh % NH;
  int tid = threadIdx.x, w = tid >> 6, lane = tid & 63;
  const u16* kbase = qkv + (size_t)b*NT_*1152 + 384 + hh*64;
  const u16* vbase = kbase + 384;

  int jr = tid >> 3, col = (tid & 7) * 8;   // jr 0..63
#pragma unroll
  for (int it = 0; it < 4; ++it){
    int j = it*64 + jr;
    if (j < 208){
      uint4 val = {0u,0u,0u,0u};
      if (j < 197) val = *(const uint4*)(kbase + (size_t)j*1152 + col);
      *(uint4*)&Ks[j*72 + col] = val;
    }
  }
#pragma unroll
  for (int it = 0; it < 4; ++it){
    int j = it*64 + jr;
    if (j < 224){
      union { uint4 v; u16 s[8]; } u;
      u.v.x = 0u; u.v.y = 0u; u.v.z = 0u; u.v.w = 0u;
      if (j < 197) u.v = *(const uint4*)(vbase + (size_t)j*1152 + col);
#pragma unroll
      for (int e = 0; e < 8; ++e) Vt[(size_t)(col+e)*232 + j] = u.s[e];
    }
  }
  __syncthreads();

  u16* myP = Ps[w];
  int fr = lane & 15, fk = lane >> 4;

  for (int qt = w; qt < 13; qt += 8){
    const u16* qrow = qkv + (size_t)(b*NT_ + qt*16 + fr)*1152 + hh*64 + fk*8;
    short8 aq0 = *(const short8*)qrow;
    short8 aq1 = *(const short8*)(qrow + 32);

    f32x4 s[13];
#pragma unroll
    for (int jt = 0; jt < 13; ++jt){
      const u16* kr = &Ks[(jt*16 + fr)*72 + fk*8];
      short8 bk0 = *(const short8*)kr;
      short8 bk1 = *(const short8*)(kr + 32);
      f32x4 z = {0.f,0.f,0.f,0.f};
      z = MFMA_BF16(aq0, bk0, z);
      z = MFMA_BF16(aq1, bk1, z);
      s[jt] = z;
    }

#pragma unroll
    for (int e = 0; e < 4; ++e){
      float mx = -1e30f;
#pragma unroll
      for (int jt = 0; jt < 13; ++jt){
        int cj = jt*16 + fr;
        float v = (cj < NT_) ? s[jt][e]*0.125f : -1e30f;
        s[jt][e] = v;
        mx = fmaxf(mx, v);
      }
#pragma unroll
      for (int d = 1; d < 16; d <<= 1) mx = fmaxf(mx, __shfl_xor(mx, d));
      float su = 0.f;
#pragma unroll
      for (int jt = 0; jt < 13; ++jt){
        float p = __expf(s[jt][e] - mx);
        s[jt][e] = p; su += p;
      }
#pragma unroll
      for (int d = 1; d < 16; d <<= 1) su += __shfl_xor(su, d);
      float ri = 1.f / su;
#pragma unroll
      for (int jt = 0; jt < 13; ++jt) s[jt][e] *= ri;
    }

    f32x4 oacc[4];
#pragma unroll
    for (int dt = 0; dt < 4; ++dt) oacc[dt] = (f32x4){0.f,0.f,0.f,0.f};
#pragma unroll
    for (int jc = 0; jc < 7; ++jc){
#pragma unroll
      for (int jtl = 0; jtl < 2; ++jtl){
        int jt = jc*2 + jtl;
#pragma unroll
        for (int e = 0; e < 4; ++e){
          u16 pv = 0;
          if (jt < 13) pv = f2bf(s[jt][e]);
          myP[(fk*4 + e)*40 + jtl*16 + fr] = pv;
        }
      }
      asm volatile("s_waitcnt lgkmcnt(0)" ::: "memory");
      short8 pa = *(const short8*)&myP[fr*40 + fk*8];
#pragma unroll
      for (int dt = 0; dt < 4; ++dt){
        short8 bv = *(const short8*)&Vt[(size_t)(dt*16 + fr)*232 + jc*32 + fk*8];
        oacc[dt] = MFMA_BF16(pa, bv, oacc[dt]);
      }
    }

#pragma unroll
    for (int dt = 0; dt < 4; ++dt)
#pragma unroll
      for (int e = 0; e < 4; ++e){
        int t = qt*16 + fk*4 + e;
        if (t < NT_)
          o[(size_t)(b*NT_ + t)*384 + hh*64 + dt*16 + fr] = f2bf(oacc[dt][e]);
      }
  }
}

// ---------------------------------------------------------------------------
extern "C" void kernel_launch(void* const* d_in, const int* in_sizes, int n_in,
                              void* d_out, int out_size, void* d_ws, size_t ws_size,
                              hipStream_t stream)
{
  (void)in_sizes; (void)n_in; (void)out_size; (void)ws_size;
  const float* x_in    = (const float*)d_in[0];
  const float* W_patch = (const float*)d_in[1];
  const float* b_patch = (const float*)d_in[2];
  const float* ln0_w   = (const float*)d_in[3];
  const float* ln0_b   = (const float*)d_in[4];
  const float* pos_emb = (const float*)d_in[5];
  const float* cls_tok = (const float*)d_in[6];
  const float* ln1_w   = (const float*)d_in[7];
  const float* ln1_b   = (const float*)d_in[8];
  const float* Wq      = (const float*)d_in[9];
  const float* Wkv     = (const float*)d_in[10];
  const float* Wo      = (const float*)d_in[11];
  const float* bo      = (const float*)d_in[12];
  const float* ln2_w   = (const float*)d_in[13];
  const float* ln2_b   = (const float*)d_in[14];
  const float* W1      = (const float*)d_in[15];
  const float* b1      = (const float*)d_in[16];
  const float* W2      = (const float*)d_in[17];
  const float* b2      = (const float*)d_in[18];
  const float* lnf_w   = (const float*)d_in[19];
  const float* lnf_b   = (const float*)d_in[20];
  const float* Whead   = (const float*)d_in[21];
  const float* bhead   = (const float*)d_in[22];

  char* ws = (char*)d_ws;
  size_t off = 0;
  auto nxt = [&](size_t bytes)->char* {
    char* p = ws + off;
    off += (bytes + 255) & ~(size_t)255;
    return p;
  };
  u16*   g_buf   = (u16*)  nxt((size_t)M_PAD * DFF_ * 2);   // also: patches
  u16*   hbuf    = (u16*)  nxt((size_t)M_PAD * D_ * 2);     // fp16 residual
  u16*   abuf    = (u16*)  nxt((size_t)M_PAD * D_ * 2);     // also: patch-embed out
  u16*   qkvbuf  = (u16*)  nxt((size_t)M_PAD * 1152 * 2);
  u16*   obuf    = (u16*)  nxt((size_t)M_PAD * D_ * 2);
  u16*   sbuf    = (u16*)  nxt((size_t)2 * M_PAD * D_ * 2); // split-K slices
  u16*   lncls   = (u16*)  nxt((size_t)B_ * D_ * 2);
  u16*   whT     = (u16*)  nxt((size_t)1024 * D_ * 2);
  u16*   wT      = (u16*)  nxt((size_t)21528576 * 2);

  const size_t SS = (size_t)M_PAD * D_;
  u16* patches = g_buf;
  u16* pebuf   = abuf;
  u16* wpT   = wT;
  u16* wqkvT = wpT   + 294912;
  u16* woT   = wqkvT + 12*442368;
  u16* w1T   = woT   + 12*147456;
  u16* w2T   = w1T   + 12*589824;

  TJobs J;
  auto setj = [&](int i, const float* s, u16* d, int N, int K, int Nsrc,
                  long long ss, long long ds, int nz){
    J.src[i]=s; J.dst[i]=d; J.N[i]=N; J.K[i]=K; J.Nsrc[i]=Nsrc;
    J.ss[i]=ss; J.ds[i]=ds; J.cnt[i]=(N/32)*(K/32)*nz;
  };
  setj(0, W_patch, wpT,             384,  768,  384, 0, 0, 1);
  setj(1, Wq,      wqkvT,           384,  384,  384, 384LL*384,  1152LL*384, 12);
  setj(2, Wkv,     wqkvT + 384*384, 768,  384,  768, 384LL*768,  1152LL*384, 12);
  setj(3, Wo,      woT,             384,  384,  384, 384LL*384,  384LL*384,  12);
  setj(4, W1,      w1T,             1536, 384, 1536, 384LL*1536, 384LL*1536, 12);
  setj(5, W2,      w2T,             384, 1536,  384, 1536LL*384, 1536LL*384, 12);
  setj(6, Whead,   whT,             1024, 384, 1000, 0, 0, 1);
  int tblocks = 0;
  for (int i = 0; i < 7; ++i) tblocks += J.cnt[i];
  transpose_all<<<tblocks, dim3(32,8), 0, stream>>>(J);

  patch_extract<<<M_PATCH, 256, 0, stream>>>(x_in, patches);
  gemm_k<0,128,128,1,8><<<3*(M_PATCH/128), 512, 0, stream>>>(patches, wpT, b_patch, pebuf, nullptr, 384, 768, 3, 0);
  assemble_h<<<M_PAD/4, 256, 0, stream>>>(pebuf, ln0_w, ln0_b, pos_emb, cls_tok, hbuf);

  for (int d = 0; d < DEPTH_; ++d){
    if (d == 0)
      ln_rows<<<M_PAD/4, 256, 0, stream>>>(hbuf, ln1_w, ln1_b, abuf, M_PAD, D_);
    else
      ln_rows_add<<<M_PAD/4, 256, 0, stream>>>(hbuf, sbuf, sbuf + SS,
                                               ln1_w + d*384, ln1_b + d*384,
                                               abuf, hbuf, M_PAD, D_);
    gemm_k<0,128,128,1,8><<<9*(M_PAD/128), 512, 0, stream>>>(abuf, wqkvT + (size_t)d*442368, nullptr, qkvbuf, nullptr, 1152, 384, 9, 0);
    attn_k<<<B_*NH, 512, 0, stream>>>(qkvbuf, obuf);
    gemm_k<4,128,128,2,8><<<dim3(3*(M_PAD/128), 2), 512, 0, stream>>>(obuf, woT + (size_t)d*147456, bo + d*384, sbuf, nullptr, 384, 384, 3, SS);
    ln_rows_add<<<M_PAD/4, 256, 0, stream>>>(hbuf, sbuf, sbuf + SS,
                                             ln2_w + d*384, ln2_b + d*384,
                                             abuf, hbuf, M_PAD, D_);
    gemm_k<2,128,128,1,8><<<12*(M_PAD/128), 512, 0, stream>>>(abuf, w1T + (size_t)d*589824, b1 + d*1536, g_buf, nullptr, 1536, 384, 12, 0);
    gemm_k<4,128,128,2,8><<<dim3(3*(M_PAD/128), 2), 512, 0, stream>>>(g_buf, w2T + (size_t)d*589824, b2 + d*384, sbuf, nullptr, 384, 1536, 3, SS);
  }

  ln_rows_add<<<B_/4, 256, 0, stream>>>(hbuf, sbuf, sbuf + SS,
                                        lnf_w, lnf_b, lncls, nullptr,
                                        B_, (size_t)NT_*D_);
  gemm_k<3,64,64,1,4><<<16, 256, 0, stream>>>(lncls, whT, bhead, nullptr, (float*)d_out, 1000, 384, 16, 0);
}